// Round 1
// baseline (328.791 us; speedup 1.0000x reference)
//
#include <hip/hip_runtime.h>

typedef __attribute__((ext_vector_type(8))) short bf16x8;
typedef __attribute__((ext_vector_type(4))) float f32x4;
typedef __attribute__((ext_vector_type(4))) unsigned short u16x4;

#define DEVFN static __device__ __forceinline__

DEVFN unsigned short f2bf(float x) {
  unsigned u = __float_as_uint(x);
  return (unsigned short)((u + 0x7fffu + ((u >> 16) & 1u)) >> 16);
}
DEVFN float bf2f(unsigned short s) { return __uint_as_float(((unsigned)s) << 16); }
// LDS tiles have 128-byte rows; XOR-swizzle bits 4-6 by row to avoid bank conflicts
DEVFN int swz(int row, int colByte) { return row * 128 + (colByte ^ ((row & 7) << 4)); }

enum { MODE_Q = 0, MODE_K = 1, MODE_V = 2, MODE_P = 3, MODE_OUT = 4 };

// C = A (MxK row-major) * W^T (W is NxK row-major), K=512, tile 128x128, BK=64.
// f32 (or bf16) inputs converted to bf16 during LDS staging.
template <int MODE, bool ABF16>
__global__ __launch_bounds__(256, 2) void gemm_nt(
    const void* __restrict__ Ap, const float* __restrict__ Wp,
    const float* __restrict__ bias, unsigned short* __restrict__ bfout,
    float* __restrict__ fout) {
  __shared__ char Als[128 * 128];
  __shared__ char Bls[128 * 128];
  const int tid = threadIdx.x;
  const int lane = tid & 63, w = tid >> 6;
  const int wr = (w >> 1) * 64, wc = (w & 1) * 64;
  const int lg = lane >> 4, lr = lane & 15;
  const int m0 = blockIdx.x * 128, n0 = blockIdx.y * 128;

  f32x4 acc[4][4];
#pragma unroll
  for (int i = 0; i < 4; i++)
#pragma unroll
    for (int j = 0; j < 4; j++) acc[i][j] = (f32x4)(0.f);

  for (int k0 = 0; k0 < 512; k0 += 64) {
    __syncthreads();
#pragma unroll
    for (int rep = 0; rep < 8; rep++) {
      int idx = rep * 1024 + tid * 4;
      int row = idx >> 6, col = idx & 63;
      uint2 pa;
      if (ABF16) {
        pa = *(const uint2*)((const unsigned short*)Ap +
                             (size_t)(m0 + row) * 512 + k0 + col);
      } else {
        float4 f = *(const float4*)((const float*)Ap +
                                    (size_t)(m0 + row) * 512 + k0 + col);
        pa.x = f2bf(f.x) | ((unsigned)f2bf(f.y) << 16);
        pa.y = f2bf(f.z) | ((unsigned)f2bf(f.w) << 16);
      }
      *(uint2*)(Als + swz(row, col * 2)) = pa;
      float4 g = *(const float4*)(Wp + (size_t)(n0 + row) * 512 + k0 + col);
      uint2 pb;
      pb.x = f2bf(g.x) | ((unsigned)f2bf(g.y) << 16);
      pb.y = f2bf(g.z) | ((unsigned)f2bf(g.w) << 16);
      *(uint2*)(Bls + swz(row, col * 2)) = pb;
    }
    __syncthreads();
#pragma unroll
    for (int ks = 0; ks < 2; ks++) {
      bf16x8 af[4], bfr[4];
#pragma unroll
      for (int i = 0; i < 4; i++)
        af[i] = *(const bf16x8*)(Als + swz(wr + i * 16 + lr, (ks * 32 + lg * 8) * 2));
#pragma unroll
      for (int j = 0; j < 4; j++)
        bfr[j] = *(const bf16x8*)(Bls + swz(wc + j * 16 + lr, (ks * 32 + lg * 8) * 2));
#pragma unroll
      for (int i = 0; i < 4; i++)
#pragma unroll
        for (int j = 0; j < 4; j++)
          acc[i][j] = __builtin_amdgcn_mfma_f32_16x16x32_bf16(af[i], bfr[j],
                                                              acc[i][j], 0, 0, 0);
    }
  }
  // epilogue: C layout col = lane&15, row = (lane>>4)*4 + reg
#pragma unroll
  for (int i = 0; i < 4; i++) {
#pragma unroll
    for (int j = 0; j < 4; j++) {
      int colg = n0 + wc + j * 16 + lr;
      float bc;
      if constexpr (MODE == MODE_P) bc = 0.f; else bc = bias[colg];
#pragma unroll
      for (int r = 0; r < 4; r++) {
        int rowg = m0 + wr + i * 16 + lg * 4 + r;
        float v = acc[i][j][r] + bc;
        if constexpr (MODE == MODE_OUT) {
          fout[(size_t)rowg * 512 + colg] = v;
        } else {
          int b = rowg >> 10, t = rowg & 1023, h = colg >> 6, dk = colg & 63;
          size_t bht = (size_t)(b * 8 + h) * 1024 + t;
          if constexpr (MODE == MODE_Q || MODE == MODE_P)
            bfout[bht * 64 + dk] = f2bf(v);
          if constexpr (MODE == MODE_K) fout[bht * 128 + dk] = v;
          if constexpr (MODE == MODE_V) {
            fout[bht * 128 + 64 + dk] = v;
            bfout[bht * 64 + dk] = f2bf(v);
          }
        }
      }
    }
  }
}

// kp = k + p (bf16), c[b,h,s] = u_h . k + v_h . p ; 16 threads per row
__global__ __launch_bounds__(256, 4) void fuse_kp(
    const float* __restrict__ kcache, const unsigned short* __restrict__ pw,
    const float* __restrict__ ub, const float* __restrict__ vb,
    unsigned short* __restrict__ kpw, float* __restrict__ cb) {
  int tid = threadIdx.x;
  int row = blockIdx.x * 16 + (tid >> 4);  // [ (b*8+h)*1024 + s ]
  int g = tid & 15;
  int h = (row >> 10) & 7;
  float4 k4 = *(const float4*)(kcache + (size_t)row * 128 + g * 4);
  u16x4 p4 = *(const u16x4*)(pw + (size_t)row * 64 + g * 4);
  float4 uu = *(const float4*)(ub + h * 64 + g * 4);
  float4 vv = *(const float4*)(vb + h * 64 + g * 4);
  float kf[4] = {k4.x, k4.y, k4.z, k4.w};
  float uf[4] = {uu.x, uu.y, uu.z, uu.w};
  float vf[4] = {vv.x, vv.y, vv.z, vv.w};
  float part = 0.f;
  unsigned short kpu[4];
#pragma unroll
  for (int j = 0; j < 4; j++) {
    float pf = bf2f((unsigned short)p4[j]);
    kpu[j] = f2bf(kf[j] + pf);
    part += uf[j] * kf[j] + vf[j] * pf;
  }
  uint2 o;
  o.x = kpu[0] | ((unsigned)kpu[1] << 16);
  o.y = kpu[2] | ((unsigned)kpu[3] << 16);
  *(uint2*)(kpw + (size_t)row * 64 + g * 4) = o;
#pragma unroll
  for (int s = 1; s < 16; s <<= 1) part += __shfl_xor(part, s, 64);
  if (g == 0) cb[row] = part;
}

// pack mask [B,T,T] int32 -> one u64 bitfield per (b,t, 64-col chunk)
__global__ __launch_bounds__(256, 8) void pack_mask(
    const int* __restrict__ m, unsigned long long* __restrict__ mb) {
  int word = blockIdx.x * 4 + (threadIdx.x >> 6);
  int lane = threadIdx.x & 63;
  int v = m[(size_t)(word >> 4) * 1024 + (word & 15) * 64 + lane];
  unsigned long long bal = __ballot(v != 0);
  if (lane == 0) mb[word] = bal;
}

// flash attention: scores = (q.kp + c)/8, online softmax, O += P.V
__global__ __launch_bounds__(256, 2) void attn_kernel(
    const unsigned short* __restrict__ qw, const unsigned short* __restrict__ kpw,
    const unsigned short* __restrict__ vw, const float* __restrict__ cb,
    const unsigned long long* __restrict__ mbits, unsigned short* __restrict__ ow) {
  __shared__ char KPls[64 * 128];
  __shared__ char VTls[64 * 128];
  __shared__ char Pls[4][16 * 128];

  const int tid = threadIdx.x;
  const int lane = tid & 63, w = tid >> 6;
  const int lg = lane >> 4, lr = lane & 15;
  const int t0 = blockIdx.x * 64;
  const int bh = blockIdx.y;
  const int b = bh >> 3, h = bh & 7;
  const float NEG = -3.0e38f;

  const size_t qrow0 = (size_t)bh * 1024 + t0 + w * 16;
  bf16x8 qf[2];
#pragma unroll
  for (int ks = 0; ks < 2; ks++)
    qf[ks] = *(const bf16x8*)(qw + (qrow0 + lr) * 64 + ks * 32 + lg * 8);

  f32x4 oacc[4];
#pragma unroll
  for (int d = 0; d < 4; d++) oacc[d] = (f32x4)(0.f);
  float mrow[4], lsum[4];
#pragma unroll
  for (int r = 0; r < 4; r++) { mrow[r] = -__builtin_inff(); lsum[r] = 0.f; }

  for (int s0 = 0; s0 < 1024; s0 += 64) {
    __syncthreads();
    const size_t kr0 = (size_t)bh * 1024 + s0;
#pragma unroll
    for (int rep = 0; rep < 4; rep++) {
      int idx = rep * 1024 + tid * 4;
      int sr = idx >> 6, c4 = idx & 63;
      uint2 kp2 = *(const uint2*)(kpw + (kr0 + sr) * 64 + c4);
      *(uint2*)(KPls + swz(sr, c4 * 2)) = kp2;
      u16x4 v4 = *(const u16x4*)(vw + (kr0 + sr) * 64 + c4);
#pragma unroll
      for (int j = 0; j < 4; j++)
        *(unsigned short*)(VTls + swz(c4 + j, sr * 2)) = (unsigned short)v4[j];
    }
    __syncthreads();

    f32x4 sacc[4];
#pragma unroll
    for (int st = 0; st < 4; st++) {
      sacc[st] = (f32x4)(0.f);
#pragma unroll
      for (int ks = 0; ks < 2; ks++) {
        bf16x8 kf = *(const bf16x8*)(KPls + swz(st * 16 + lr, (ks * 32 + lg * 8) * 2));
        sacc[st] = __builtin_amdgcn_mfma_f32_16x16x32_bf16(qf[ks], kf, sacc[st], 0, 0, 0);
      }
    }

    unsigned long long mb[4];
#pragma unroll
    for (int r = 0; r < 4; r++)
      mb[r] = mbits[((size_t)b * 1024 + (t0 + w * 16 + lg * 4 + r)) * 16 + (s0 >> 6)];
    float cv[4];
#pragma unroll
    for (int st = 0; st < 4; st++)
      cv[st] = cb[(size_t)bh * 1024 + s0 + st * 16 + lr];

    float sv[4][4];
#pragma unroll
    for (int st = 0; st < 4; st++)
#pragma unroll
      for (int r = 0; r < 4; r++) {
        float x = (sacc[st][r] + cv[st]) * 0.125f;
        sv[st][r] = ((mb[r] >> (st * 16 + lr)) & 1ull) ? x : NEG;
      }

    float scale[4];
#pragma unroll
    for (int r = 0; r < 4; r++) {
      float mx = fmaxf(fmaxf(sv[0][r], sv[1][r]), fmaxf(sv[2][r], sv[3][r]));
#pragma unroll
      for (int o = 1; o < 16; o <<= 1) mx = fmaxf(mx, __shfl_xor(mx, o, 64));
      float mn = fmaxf(mrow[r], mx);
      scale[r] = (mn == mrow[r]) ? 1.f : __expf(mrow[r] - mn);
      mrow[r] = mn;
    }
    float rs[4] = {0.f, 0.f, 0.f, 0.f};
    unsigned short pb[4][4];
#pragma unroll
    for (int st = 0; st < 4; st++)
#pragma unroll
      for (int r = 0; r < 4; r++) {
        bool on = (mb[r] >> (st * 16 + lr)) & 1ull;
        float p = on ? __expf(sv[st][r] - mrow[r]) : 0.f;
        rs[r] += p;
        pb[st][r] = f2bf(p);
      }
#pragma unroll
    for (int r = 0; r < 4; r++) {
      float s = rs[r];
#pragma unroll
      for (int o = 1; o < 16; o <<= 1) s += __shfl_xor(s, o, 64);
      lsum[r] = lsum[r] * scale[r] + s;
    }
    // P back through LDS to get MFMA A-operand layout
#pragma unroll
    for (int st = 0; st < 4; st++)
#pragma unroll
      for (int r = 0; r < 4; r++)
        *(unsigned short*)(Pls[w] + swz(lg * 4 + r, (st * 16 + lr) * 2)) = pb[st][r];
#pragma unroll
    for (int d = 0; d < 4; d++)
#pragma unroll
      for (int r = 0; r < 4; r++) oacc[d][r] *= scale[r];
#pragma unroll
    for (int ks = 0; ks < 2; ks++) {
      bf16x8 pf = *(const bf16x8*)(Pls[w] + swz(lr, (ks * 32 + lg * 8) * 2));
#pragma unroll
      for (int d = 0; d < 4; d++) {
        bf16x8 vf = *(const bf16x8*)(VTls + swz(d * 16 + lr, (ks * 32 + lg * 8) * 2));
        oacc[d] = __builtin_amdgcn_mfma_f32_16x16x32_bf16(pf, vf, oacc[d], 0, 0, 0);
      }
    }
  }
#pragma unroll
  for (int d = 0; d < 4; d++)
#pragma unroll
    for (int r = 0; r < 4; r++) {
      int t = t0 + w * 16 + lg * 4 + r;
      float o = (lsum[r] > 0.f) ? oacc[d][r] / lsum[r] : 0.f;
      ow[((size_t)b * 1024 + t) * 512 + h * 64 + d * 16 + lr] = f2bf(o);
    }
}

extern "C" void kernel_launch(void* const* d_in, const int* in_sizes, int n_in,
                              void* d_out, int out_size, void* d_ws, size_t ws_size,
                              hipStream_t stream) {
  const float* query = (const float*)d_in[0];
  const float* key = (const float*)d_in[1];
  const float* value = (const float*)d_in[2];
  const int* amask = (const int*)d_in[3];
  const float* pos = (const float*)d_in[4];
  const float* Wq = (const float*)d_in[5];
  const float* bq = (const float*)d_in[6];
  const float* Wk = (const float*)d_in[7];
  const float* bk = (const float*)d_in[8];
  const float* Wv = (const float*)d_in[9];
  const float* bv = (const float*)d_in[10];
  const float* Wpos = (const float*)d_in[11];
  const float* Wout = (const float*)d_in[12];
  const float* bout = (const float*)d_in[13];
  const float* pbu = (const float*)d_in[14];
  const float* pbv = (const float*)d_in[15];

  float* out = (float*)d_out;                    // [8192, 512]
  float* cache = out + (size_t)8192 * 512;       // [64, 1024, 128]

  char* ws = (char*)d_ws;
  const size_t QSZ = (size_t)8 * 8 * 1024 * 64 * 2;  // 8,388,608 B per bf16 [B,H,T,DK]
  unsigned short* ws_q = (unsigned short*)(ws);
  unsigned short* ws_kp = (unsigned short*)(ws + QSZ);
  unsigned short* ws_v = (unsigned short*)(ws + 2 * QSZ);
  unsigned short* ws_p = (unsigned short*)(ws + 3 * QSZ);  // reused as attn out
  float* cbuf = (float*)(ws + 4 * QSZ);                    // 256 KB
  unsigned long long* mbits = (unsigned long long*)(ws + 4 * QSZ + (size_t)(1 << 20));  // 1 MB
  unsigned short* ws_o = ws_p;

  dim3 blk(256);
  dim3 gg(64, 4);
  gemm_nt<MODE_Q, false><<<gg, blk, 0, stream>>>(query, Wq, bq, ws_q, nullptr);
  gemm_nt<MODE_K, false><<<gg, blk, 0, stream>>>(key, Wk, bk, nullptr, cache);
  gemm_nt<MODE_V, false><<<gg, blk, 0, stream>>>(value, Wv, bv, ws_v, cache);
  gemm_nt<MODE_P, false><<<gg, blk, 0, stream>>>(pos, Wpos, nullptr, ws_p, nullptr);
  fuse_kp<<<dim3(4096), blk, 0, stream>>>(cache, ws_p, pbu, pbv, ws_kp, cbuf);
  pack_mask<<<dim3(32768), blk, 0, stream>>>(amask, mbits);
  attn_kernel<<<dim3(16, 64), blk, 0, stream>>>(ws_q, ws_kp, ws_v, cbuf, mbits, ws_o);
  gemm_nt<MODE_OUT, true><<<gg, blk, 0, stream>>>(ws_o, Wout, bout, nullptr, out);
}

// Round 3
// 161.102 us; speedup vs baseline: 2.0409x; 2.0409x over previous
//
#include <hip/hip_runtime.h>

typedef __attribute__((ext_vector_type(8))) short bf16x8;
typedef __attribute__((ext_vector_type(4))) float f32x4;
typedef __attribute__((ext_vector_type(4))) unsigned short u16x4;

#define DEVFN static __device__ __forceinline__

DEVFN unsigned short f2bf(float x) {
  unsigned u = __float_as_uint(x);
  return (unsigned short)((u + 0x7fffu + ((u >> 16) & 1u)) >> 16);
}
DEVFN unsigned pk2(float x, float y) {
  return (unsigned)f2bf(x) | ((unsigned)f2bf(y) << 16);
}
DEVFN float bf2f(unsigned short s) { return __uint_as_float(((unsigned)s) << 16); }

// async 16B global->LDS. LDS dest must be wave-uniform base (HW adds lane*16).
DEVFN void gld16(const void* g, void* l) {
  __builtin_amdgcn_global_load_lds(
      (const __attribute__((address_space(1))) unsigned int*)g,
      (__attribute__((address_space(3))) unsigned int*)l, 16, 0, 0);
}

// convert 4 weight matrices f32->bf16 (or 1, grid.y=1)
__global__ __launch_bounds__(256, 8) void prep_w(
    const float* __restrict__ s0, const float* __restrict__ s1,
    const float* __restrict__ s2, const float* __restrict__ s3,
    unsigned short* __restrict__ dst) {
  const float* s = blockIdx.y == 0 ? s0 : blockIdx.y == 1 ? s1
                   : blockIdx.y == 2 ? s2 : s3;
  size_t base = (size_t)blockIdx.y * 262144;
  size_t idx = ((size_t)blockIdx.x * 256 + threadIdx.x) * 8;
  float4 a = *(const float4*)(s + idx);
  float4 b = *(const float4*)(s + idx + 4);
  uint4 o;
  o.x = pk2(a.x, a.y); o.y = pk2(a.z, a.w);
  o.z = pk2(b.x, b.y); o.w = pk2(b.z, b.w);
  *(uint4*)(dst + base + idx) = o;
}

// C = A (8192xK=512) * W^T (W N=512xK=512 row-major). Tile 128x64, BK=64,
// double-buffered LDS, prefetch-before-compute. LDS layout: rows of 128B,
// 16B chunk c of row r stored at chunk (c ^ (r&7))  -> conflict-free ds_read_b128.
// mode 0=Q 1=K 2=V 3=P (blockIdx.z), 4=OUT.
template <bool AF32>
__global__ __launch_bounds__(256, 3) void gemm_bt(
    const void* A0, const void* A1, const void* A2, const void* A3,
    const unsigned short* __restrict__ Wb, const float* b0, const float* b1,
    const float* b2, int mode_base,
    unsigned short* __restrict__ qout, float* __restrict__ cache,
    unsigned short* __restrict__ vtout, unsigned short* __restrict__ pout,
    float* __restrict__ fout) {
  __shared__ alignas(16) char Als[2][128 * 128];
  __shared__ alignas(16) char Bls[2][64 * 128];
  const int tid = threadIdx.x;
  const int lane = tid & 63, w = tid >> 6;
  const int wr = (w >> 1) * 64, wc = (w & 1) * 32;
  const int lg = lane >> 4, lr = lane & 15;
  const int m0 = blockIdx.x * 128, n0 = blockIdx.y * 64;
  const int mode = mode_base + blockIdx.z;
  const void* Ap = (mode == 1) ? A1 : (mode == 2) ? A2 : (mode == 3) ? A3 : A0;
  const unsigned short* Wp = Wb + (mode_base ? 0 : blockIdx.z * 262144);
  const float* bias = (mode == 0 || mode == 4) ? b0
                      : (mode == 1) ? b1 : (mode == 2) ? b2 : nullptr;

  auto stageA = [&](int buf, int k0) {
    if constexpr (AF32) {
      const float* Af = (const float*)Ap;
#pragma unroll
      for (int rep = 0; rep < 4; rep++) {
        int cid = rep * 256 + tid;
        int row = cid >> 3, c = cid & 7;
        const float* src = Af + (size_t)(m0 + row) * 512 + k0 + c * 8;
        float4 fa = *(const float4*)(src);
        float4 fb = *(const float4*)(src + 4);
        uint4 o;
        o.x = pk2(fa.x, fa.y); o.y = pk2(fa.z, fa.w);
        o.z = pk2(fb.x, fb.y); o.w = pk2(fb.z, fb.w);
        *(uint4*)(Als[buf] + row * 128 + ((c ^ (row & 7)) << 4)) = o;
      }
    } else {
      const unsigned short* Ab = (const unsigned short*)Ap;
#pragma unroll
      for (int rep = 0; rep < 4; rep++) {
        int cid = rep * 256 + tid;
        int row = cid >> 3, c = cid & 7;
        gld16(Ab + (size_t)(m0 + row) * 512 + k0 + ((c ^ (row & 7)) << 3),
              Als[buf] + ((rep * 256 + (w << 6)) << 4));
      }
    }
  };
  auto stageB = [&](int buf, int k0) {
#pragma unroll
    for (int rep = 0; rep < 2; rep++) {
      int cid = rep * 256 + tid;
      int row = cid >> 3, c = cid & 7;
      gld16(Wp + (size_t)(n0 + row) * 512 + k0 + ((c ^ (row & 7)) << 3),
            Bls[buf] + ((rep * 256 + (w << 6)) << 4));
    }
  };

  f32x4 acc[4][2];
#pragma unroll
  for (int i = 0; i < 4; i++)
#pragma unroll
    for (int j = 0; j < 2; j++) acc[i][j] = (f32x4)(0.f);

  stageA(0, 0);
  stageB(0, 0);
  __syncthreads();
  int cur = 0;
  for (int k0 = 0; k0 < 512; k0 += 64) {
    if (k0 + 64 < 512) { stageA(cur ^ 1, k0 + 64); stageB(cur ^ 1, k0 + 64); }
#pragma unroll
    for (int ks = 0; ks < 2; ks++) {
      bf16x8 af[4], bfr[2];
#pragma unroll
      for (int i = 0; i < 4; i++) {
        int row = wr + i * 16 + lr;
        af[i] = *(const bf16x8*)(Als[cur] + row * 128 + (((ks * 4 + lg) ^ (row & 7)) << 4));
      }
#pragma unroll
      for (int j = 0; j < 2; j++) {
        int row = wc + j * 16 + lr;
        bfr[j] = *(const bf16x8*)(Bls[cur] + row * 128 + (((ks * 4 + lg) ^ (row & 7)) << 4));
      }
#pragma unroll
      for (int i = 0; i < 4; i++)
#pragma unroll
        for (int j = 0; j < 2; j++)
          acc[i][j] = __builtin_amdgcn_mfma_f32_16x16x32_bf16(af[i], bfr[j],
                                                              acc[i][j], 0, 0, 0);
    }
    __syncthreads();
    cur ^= 1;
  }

#pragma unroll
  for (int i = 0; i < 4; i++) {
#pragma unroll
    for (int j = 0; j < 2; j++) {
      int colg = n0 + wc + j * 16 + lr;
      float bc = bias ? bias[colg] : 0.f;
      if (mode == 4) {
#pragma unroll
        for (int r = 0; r < 4; r++) {
          int rowg = m0 + wr + i * 16 + lg * 4 + r;
          fout[(size_t)rowg * 512 + colg] = acc[i][j][r] + bc;
        }
      } else {
        int rbase = m0 + wr + i * 16 + lg * 4;
        int b = rbase >> 10, t = rbase & 1023, h = colg >> 6, dk = colg & 63;
        size_t bht = (size_t)(b * 8 + h) * 1024 + t;
        if (mode == 0) {
#pragma unroll
          for (int r = 0; r < 4; r++) qout[(bht + r) * 64 + dk] = f2bf(acc[i][j][r] + bc);
        } else if (mode == 1) {
#pragma unroll
          for (int r = 0; r < 4; r++) cache[(bht + r) * 128 + dk] = acc[i][j][r] + bc;
        } else if (mode == 3) {
#pragma unroll
          for (int r = 0; r < 4; r++) pout[(bht + r) * 64 + dk] = f2bf(acc[i][j][r] + bc);
        } else {
          u16x4 pv;
#pragma unroll
          for (int r = 0; r < 4; r++) {
            float v = acc[i][j][r] + bc;
            cache[(bht + r) * 128 + 64 + dk] = v;
            pv[r] = f2bf(v);
          }
          *(u16x4*)(vtout + ((size_t)(b * 8 + h) * 64 + dk) * 1024 + t) = pv;
        }
      }
    }
  }
}

// in-place: p (bf16, in kp buffer) + k (f32 cache) -> kp bf16; c = u.k + v.p
__global__ __launch_bounds__(256, 4) void fuse_kp(
    const float* __restrict__ kcache, unsigned short* __restrict__ kp,
    const float* __restrict__ ub, const float* __restrict__ vb,
    float* __restrict__ cb) {
  int tid = threadIdx.x;
  int row = blockIdx.x * 16 + (tid >> 4);
  int g = tid & 15;
  int h = (row >> 10) & 7;
  float4 k4 = *(const float4*)(kcache + (size_t)row * 128 + g * 4);
  u16x4 p4 = *(const u16x4*)(kp + (size_t)row * 64 + g * 4);
  float4 uu = *(const float4*)(ub + h * 64 + g * 4);
  float4 vv = *(const float4*)(vb + h * 64 + g * 4);
  float kf[4] = {k4.x, k4.y, k4.z, k4.w};
  float uf[4] = {uu.x, uu.y, uu.z, uu.w};
  float vf[4] = {vv.x, vv.y, vv.z, vv.w};
  float part = 0.f;
  unsigned short kpu[4];
#pragma unroll
  for (int j = 0; j < 4; j++) {
    float pf = bf2f((unsigned short)p4[j]);
    kpu[j] = f2bf(kf[j] + pf);
    part += uf[j] * kf[j] + vf[j] * pf;
  }
  uint2 o;
  o.x = kpu[0] | ((unsigned)kpu[1] << 16);
  o.y = kpu[2] | ((unsigned)kpu[3] << 16);
  *(uint2*)(kp + (size_t)row * 64 + g * 4) = o;
#pragma unroll
  for (int s = 1; s < 16; s <<= 1) part += __shfl_xor(part, s, 64);
  if (g == 0) cb[row] = part;
}

__global__ __launch_bounds__(256, 8) void pack_mask(
    const int* __restrict__ m, unsigned long long* __restrict__ mb) {
  int word = blockIdx.x * 4 + (threadIdx.x >> 6);
  int lane = threadIdx.x & 63;
  int v = m[(size_t)(word >> 4) * 1024 + (word & 15) * 64 + lane];
  unsigned long long bal = __ballot(v != 0);
  if (lane == 0) mb[word] = bal;
}

// flash attn: scores = (q.kp + c)*0.125, exp2-domain online softmax, O = P.V
__global__ __launch_bounds__(256, 4) void attn_kernel(
    const unsigned short* __restrict__ qw, const unsigned short* __restrict__ kpw,
    const unsigned short* __restrict__ vtw, const float* __restrict__ cb,
    const unsigned long long* __restrict__ mbits, unsigned short* __restrict__ ow) {
  __shared__ alignas(16) char KPls[2][64 * 128];
  __shared__ alignas(16) char VTls[2][64 * 128];
  __shared__ alignas(16) char Pls[4][16 * 128];

  const int tid = threadIdx.x;
  const int lane = tid & 63, w = tid >> 6;
  const int lg = lane >> 4, lr = lane & 15;
  const int t0 = blockIdx.x * 64;
  const int bh = blockIdx.y;
  const int b = bh >> 3, h = bh & 7;
  const float NEG = -3.0e38f;
  const float SC = 0.125f * 1.44269504088896f;  // log2e folded in

  const size_t qrow0 = (size_t)bh * 1024 + t0 + w * 16;
  bf16x8 qf[2];
#pragma unroll
  for (int ks = 0; ks < 2; ks++)
    qf[ks] = *(const bf16x8*)(qw + (qrow0 + lr) * 64 + ks * 32 + lg * 8);

  f32x4 oacc[4];
#pragma unroll
  for (int d = 0; d < 4; d++) oacc[d] = (f32x4)(0.f);
  float mrow[4], lsum[4];
#pragma unroll
  for (int r = 0; r < 4; r++) { mrow[r] = -__builtin_inff(); lsum[r] = 0.f; }

  auto stage = [&](int buf, int s0) {
    const size_t kr0 = (size_t)bh * 1024 + s0;
#pragma unroll
    for (int rep = 0; rep < 2; rep++) {
      int cid = rep * 256 + tid;
      int row = cid >> 3, c = cid & 7;
      gld16(kpw + (kr0 + row) * 64 + ((c ^ (row & 7)) << 3),
            KPls[buf] + ((rep * 256 + (w << 6)) << 4));
      gld16(vtw + ((size_t)bh * 64 + row) * 1024 + s0 + ((c ^ (row & 7)) << 3),
            VTls[buf] + ((rep * 256 + (w << 6)) << 4));
    }
  };

  stage(0, 0);
  __syncthreads();
  int cur = 0;
  for (int s0 = 0; s0 < 1024; s0 += 64) {
    if (s0 + 64 < 1024) stage(cur ^ 1, s0 + 64);

    f32x4 sacc[4];
#pragma unroll
    for (int st = 0; st < 4; st++) {
      sacc[st] = (f32x4)(0.f);
#pragma unroll
      for (int ks = 0; ks < 2; ks++) {
        int row = st * 16 + lr;
        bf16x8 kf = *(const bf16x8*)(KPls[cur] + row * 128 +
                                     (((ks * 4 + lg) ^ (row & 7)) << 4));
        sacc[st] = __builtin_amdgcn_mfma_f32_16x16x32_bf16(qf[ks], kf, sacc[st], 0, 0, 0);
      }
    }

    unsigned long long mb[4];
#pragma unroll
    for (int r = 0; r < 4; r++)
      mb[r] = mbits[((size_t)b * 1024 + (t0 + w * 16 + lg * 4 + r)) * 16 + (s0 >> 6)];
    float cv[4];
#pragma unroll
    for (int st = 0; st < 4; st++)
      cv[st] = cb[(size_t)bh * 1024 + s0 + st * 16 + lr];

    float sv[4][4];
#pragma unroll
    for (int st = 0; st < 4; st++)
#pragma unroll
      for (int r = 0; r < 4; r++) {
        float x = (sacc[st][r] + cv[st]) * SC;
        sv[st][r] = ((mb[r] >> (st * 16 + lr)) & 1ull) ? x : NEG;
      }

    float scale[4];
#pragma unroll
    for (int r = 0; r < 4; r++) {
      float mx = fmaxf(fmaxf(sv[0][r], sv[1][r]), fmaxf(sv[2][r], sv[3][r]));
#pragma unroll
      for (int o = 1; o < 16; o <<= 1) mx = fmaxf(mx, __shfl_xor(mx, o, 64));
      float mn = fmaxf(mrow[r], mx);
      scale[r] = (mn == mrow[r]) ? 1.f : exp2f(mrow[r] - mn);
      mrow[r] = mn;
    }
    float rs[4] = {0.f, 0.f, 0.f, 0.f};
    unsigned short pb[4][4];
#pragma unroll
    for (int st = 0; st < 4; st++)
#pragma unroll
      for (int r = 0; r < 4; r++) {
        bool on = (mb[r] >> (st * 16 + lr)) & 1ull;
        float p = on ? exp2f(sv[st][r] - mrow[r]) : 0.f;
        rs[r] += p;
        pb[st][r] = f2bf(p);
      }
#pragma unroll
    for (int r = 0; r < 4; r++) {
      float s = rs[r];
#pragma unroll
      for (int o = 1; o < 16; o <<= 1) s += __shfl_xor(s, o, 64);
      lsum[r] = lsum[r] * scale[r] + s;
    }
#pragma unroll
    for (int st = 0; st < 4; st++)
#pragma unroll
      for (int r = 0; r < 4; r++) {
        int row = lg * 4 + r;
        *(unsigned short*)(Pls[w] + row * 128 +
                           (((st * 16 + lr) * 2) ^ ((row & 7) << 4))) = pb[st][r];
      }
#pragma unroll
    for (int d = 0; d < 4; d++)
#pragma unroll
      for (int r = 0; r < 4; r++) oacc[d][r] *= scale[r];
#pragma unroll
    for (int ks = 0; ks < 2; ks++) {
      bf16x8 pf = *(const bf16x8*)(Pls[w] + lr * 128 +
                                   (((ks * 4 + lg) ^ (lr & 7)) << 4));
#pragma unroll
      for (int d = 0; d < 4; d++) {
        int row = d * 16 + lr;
        bf16x8 vf = *(const bf16x8*)(VTls[cur] + row * 128 +
                                     (((ks * 4 + lg) ^ (row & 7)) << 4));
        oacc[d] = __builtin_amdgcn_mfma_f32_16x16x32_bf16(pf, vf, oacc[d], 0, 0, 0);
      }
    }
    __syncthreads();
    cur ^= 1;
  }
#pragma unroll
  for (int d = 0; d < 4; d++)
#pragma unroll
    for (int r = 0; r < 4; r++) {
      int t = t0 + w * 16 + lg * 4 + r;
      float o = (lsum[r] > 0.f) ? oacc[d][r] / lsum[r] : 0.f;
      ow[((size_t)b * 1024 + t) * 512 + h * 64 + d * 16 + lr] = f2bf(o);
    }
}

extern "C" void kernel_launch(void* const* d_in, const int* in_sizes, int n_in,
                              void* d_out, int out_size, void* d_ws, size_t ws_size,
                              hipStream_t stream) {
  const float* query = (const float*)d_in[0];
  const float* key = (const float*)d_in[1];
  const float* value = (const float*)d_in[2];
  const int* amask = (const int*)d_in[3];
  const float* pos = (const float*)d_in[4];
  const float* Wq = (const float*)d_in[5];
  const float* bq = (const float*)d_in[6];
  const float* Wk = (const float*)d_in[7];
  const float* bk = (const float*)d_in[8];
  const float* Wv = (const float*)d_in[9];
  const float* bv = (const float*)d_in[10];
  const float* Wpos = (const float*)d_in[11];
  const float* Wout = (const float*)d_in[12];
  const float* bout = (const float*)d_in[13];
  const float* pbu = (const float*)d_in[14];
  const float* pbv = (const float*)d_in[15];

  float* out = (float*)d_out;               // [8192,512] f32
  float* cache = out + (size_t)8192 * 512;  // [64,1024,128] f32

  char* ws = (char*)d_ws;
  unsigned short* ws_q = (unsigned short*)(ws);                     // 8.39 MB
  unsigned short* ws_kp = (unsigned short*)(ws + 8388608);          // 8.39 MB (p, then kp in-place)
  unsigned short* ws_vt = (unsigned short*)(ws + 16777216);         // 8.39 MB (V^T bf16)
  unsigned short* ws_o = (unsigned short*)(ws + 25165824);          // 8.39 MB (attn out)
  unsigned short* W4 = ws_o;                                        // 2.10 MB, dead before attn
  float* cbuf = (float*)(ws + 33554432);                            // 0.26 MB
  unsigned long long* mbits = (unsigned long long*)(ws + 33816576); // 1.05 MB
  unsigned short* Woutb = ws_q;                                     // reused after attn

  dim3 blk(256);
  prep_w<<<dim3(128, 4), blk, 0, stream>>>(Wq, Wk, Wv, Wpos, W4);
  gemm_bt<true><<<dim3(64, 8, 4), blk, 0, stream>>>(
      query, key, value, pos, W4, bq, bk, bv, 0, ws_q, cache, ws_vt, ws_kp, nullptr);
  fuse_kp<<<dim3(4096), blk, 0, stream>>>(cache, ws_kp, pbu, pbv, cbuf);
  pack_mask<<<dim3(32768), blk, 0, stream>>>(amask, mbits);
  attn_kernel<<<dim3(16, 64), blk, 0, stream>>>(ws_q, ws_kp, ws_vt, cbuf, mbits, ws_o);
  prep_w<<<dim3(128, 1), blk, 0, stream>>>(Wout, Wout, Wout, Wout, Woutb);
  gemm_bt<false><<<dim3(64, 8, 1), blk, 0, stream>>>(
      ws_o, nullptr, nullptr, nullptr, Woutb, bout, nullptr, nullptr, 4,
      nullptr, nullptr, nullptr, nullptr, out);
}

// Round 4
// 161.028 us; speedup vs baseline: 2.0418x; 1.0005x over previous
//
#include <hip/hip_runtime.h>

typedef __attribute__((ext_vector_type(8))) short bf16x8;
typedef __attribute__((ext_vector_type(4))) float f32x4;
typedef __attribute__((ext_vector_type(4))) unsigned short u16x4;

#define DEVFN static __device__ __forceinline__

// hardware packed f32->bf16 (RNE): lo -> low16, hi -> high16
DEVFN unsigned cvtpk(float lo, float hi) {
  unsigned r;
  asm("v_cvt_pk_bf16_f32 %0, %1, %2" : "=v"(r) : "v"(lo), "v"(hi));
  return r;
}
DEVFN unsigned short cvt1(float x) {
  unsigned r;
  asm("v_cvt_pk_bf16_f32 %0, %1, %1" : "=v"(r) : "v"(x));
  return (unsigned short)r;
}
DEVFN float bf2f(unsigned short s) { return __uint_as_float(((unsigned)s) << 16); }

// async 16B global->LDS. LDS dest must be wave-uniform base (HW adds lane*16).
DEVFN void gld16(const void* g, void* l) {
  __builtin_amdgcn_global_load_lds(
      (const __attribute__((address_space(1))) unsigned int*)g,
      (__attribute__((address_space(3))) unsigned int*)l, 16, 0, 0);
}

// convert 4 weight matrices f32->bf16 (or 1, grid.y=1)
__global__ __launch_bounds__(256, 8) void prep_w(
    const float* __restrict__ s0, const float* __restrict__ s1,
    const float* __restrict__ s2, const float* __restrict__ s3,
    unsigned short* __restrict__ dst) {
  const float* s = blockIdx.y == 0 ? s0 : blockIdx.y == 1 ? s1
                   : blockIdx.y == 2 ? s2 : s3;
  size_t base = (size_t)blockIdx.y * 262144;
  size_t idx = ((size_t)blockIdx.x * 256 + threadIdx.x) * 8;
  float4 a = *(const float4*)(s + idx);
  float4 b = *(const float4*)(s + idx + 4);
  uint4 o;
  o.x = cvtpk(a.x, a.y); o.y = cvtpk(a.z, a.w);
  o.z = cvtpk(b.x, b.y); o.w = cvtpk(b.z, b.w);
  *(uint4*)(dst + base + idx) = o;
}

// C = A (8192xK=512) * W^T (W N=512xK=512 row-major). Tile 128x64, BK=64,
// double-buffered LDS, prefetch-before-compute. LDS rows 128B; 16B chunk c of
// row r stored at chunk (c ^ (r&7)) -> conflict-free ds_read_b128.
// mode 0=Q 1=K 2=V 3=P (blockIdx.z), 4=OUT.
template <bool AF32>
__global__ __launch_bounds__(256, 3) void gemm_bt(
    const void* A0, const void* A1, const void* A2, const void* A3,
    const unsigned short* __restrict__ Wb, const float* b0, const float* b1,
    const float* b2, int mode_base,
    unsigned short* __restrict__ qout, float* __restrict__ cache,
    unsigned short* __restrict__ vtout, unsigned short* __restrict__ pout,
    float* __restrict__ fout) {
  __shared__ alignas(16) char Als[2][128 * 128];
  __shared__ alignas(16) char Bls[2][64 * 128];
  const int tid = threadIdx.x;
  const int lane = tid & 63, w = tid >> 6;
  const int wr = (w >> 1) * 64, wc = (w & 1) * 32;
  const int lg = lane >> 4, lr = lane & 15;
  const int m0 = blockIdx.x * 128, n0 = blockIdx.y * 64;
  const int mode = mode_base + blockIdx.z;
  const void* Ap = (mode == 1) ? A1 : (mode == 2) ? A2 : (mode == 3) ? A3 : A0;
  const unsigned short* Wp = Wb + (mode_base ? 0 : blockIdx.z * 262144);
  const float* bias = (mode == 0 || mode == 4) ? b0
                      : (mode == 1) ? b1 : (mode == 2) ? b2 : nullptr;

  auto stageA = [&](int buf, int k0) {
    if constexpr (AF32) {
      const float* Af = (const float*)Ap;
#pragma unroll
      for (int rep = 0; rep < 4; rep++) {
        int cid = rep * 256 + tid;
        int row = cid >> 3, c = cid & 7;
        const float* src = Af + (size_t)(m0 + row) * 512 + k0 + c * 8;
        float4 fa = *(const float4*)(src);
        float4 fb = *(const float4*)(src + 4);
        uint4 o;
        o.x = cvtpk(fa.x, fa.y); o.y = cvtpk(fa.z, fa.w);
        o.z = cvtpk(fb.x, fb.y); o.w = cvtpk(fb.z, fb.w);
        *(uint4*)(Als[buf] + row * 128 + ((c ^ (row & 7)) << 4)) = o;
      }
    } else {
      const unsigned short* Ab = (const unsigned short*)Ap;
#pragma unroll
      for (int rep = 0; rep < 4; rep++) {
        int cid = rep * 256 + tid;
        int row = cid >> 3, c = cid & 7;
        gld16(Ab + (size_t)(m0 + row) * 512 + k0 + ((c ^ (row & 7)) << 3),
              Als[buf] + ((rep * 256 + (w << 6)) << 4));
      }
    }
  };
  auto stageB = [&](int buf, int k0) {
#pragma unroll
    for (int rep = 0; rep < 2; rep++) {
      int cid = rep * 256 + tid;
      int row = cid >> 3, c = cid & 7;
      gld16(Wp + (size_t)(n0 + row) * 512 + k0 + ((c ^ (row & 7)) << 3),
            Bls[buf] + ((rep * 256 + (w << 6)) << 4));
    }
  };

  f32x4 acc[4][2];
#pragma unroll
  for (int i = 0; i < 4; i++)
#pragma unroll
    for (int j = 0; j < 2; j++) acc[i][j] = (f32x4)(0.f);

  stageA(0, 0);
  stageB(0, 0);
  __syncthreads();
  int cur = 0;
  for (int k0 = 0; k0 < 512; k0 += 64) {
    if (k0 + 64 < 512) { stageA(cur ^ 1, k0 + 64); stageB(cur ^ 1, k0 + 64); }
#pragma unroll
    for (int ks = 0; ks < 2; ks++) {
      bf16x8 af[4], bfr[2];
#pragma unroll
      for (int i = 0; i < 4; i++) {
        int row = wr + i * 16 + lr;
        af[i] = *(const bf16x8*)(Als[cur] + row * 128 + (((ks * 4 + lg) ^ (row & 7)) << 4));
      }
#pragma unroll
      for (int j = 0; j < 2; j++) {
        int row = wc + j * 16 + lr;
        bfr[j] = *(const bf16x8*)(Bls[cur] + row * 128 + (((ks * 4 + lg) ^ (row & 7)) << 4));
      }
#pragma unroll
      for (int i = 0; i < 4; i++)
#pragma unroll
        for (int j = 0; j < 2; j++)
          acc[i][j] = __builtin_amdgcn_mfma_f32_16x16x32_bf16(af[i], bfr[j],
                                                              acc[i][j], 0, 0, 0);
    }
    __syncthreads();
    cur ^= 1;
  }

#pragma unroll
  for (int i = 0; i < 4; i++) {
#pragma unroll
    for (int j = 0; j < 2; j++) {
      int colg = n0 + wc + j * 16 + lr;
      float bc = bias ? bias[colg] : 0.f;
      if (mode == 4) {
#pragma unroll
        for (int r = 0; r < 4; r++) {
          int rowg = m0 + wr + i * 16 + lg * 4 + r;
          fout[(size_t)rowg * 512 + colg] = acc[i][j][r] + bc;
        }
      } else {
        int rbase = m0 + wr + i * 16 + lg * 4;
        int b = rbase >> 10, t = rbase & 1023, h = colg >> 6, dk = colg & 63;
        size_t bht = (size_t)(b * 8 + h) * 1024 + t;
        if (mode == 0) {
#pragma unroll
          for (int r = 0; r < 4; r++) qout[(bht + r) * 64 + dk] = cvt1(acc[i][j][r] + bc);
        } else if (mode == 1) {
#pragma unroll
          for (int r = 0; r < 4; r++) cache[(bht + r) * 128 + dk] = acc[i][j][r] + bc;
        } else if (mode == 3) {
#pragma unroll
          for (int r = 0; r < 4; r++) pout[(bht + r) * 64 + dk] = cvt1(acc[i][j][r]);
        } else {
          float vv[4];
#pragma unroll
          for (int r = 0; r < 4; r++) {
            vv[r] = acc[i][j][r] + bc;
            cache[(bht + r) * 128 + 64 + dk] = vv[r];
          }
          uint2 pv;
          pv.x = cvtpk(vv[0], vv[1]);
          pv.y = cvtpk(vv[2], vv[3]);
          *(uint2*)(vtout + ((size_t)(b * 8 + h) * 64 + dk) * 1024 + t) = pv;
        }
      }
    }
  }
}

// in-place: p (bf16, in kp buffer) + k (f32 cache) -> kp bf16; c = u.k + v.p
__global__ __launch_bounds__(256, 4) void fuse_kp(
    const float* __restrict__ kcache, unsigned short* __restrict__ kp,
    const float* __restrict__ ub, const float* __restrict__ vb,
    float* __restrict__ cb) {
  int tid = threadIdx.x;
  int row = blockIdx.x * 16 + (tid >> 4);
  int g = tid & 15;
  int h = (row >> 10) & 7;
  float4 k4 = *(const float4*)(kcache + (size_t)row * 128 + g * 4);
  u16x4 p4 = *(const u16x4*)(kp + (size_t)row * 64 + g * 4);
  float4 uu = *(const float4*)(ub + h * 64 + g * 4);
  float4 vv = *(const float4*)(vb + h * 64 + g * 4);
  float kf[4] = {k4.x, k4.y, k4.z, k4.w};
  float uf[4] = {uu.x, uu.y, uu.z, uu.w};
  float vf[4] = {vv.x, vv.y, vv.z, vv.w};
  float part = 0.f;
  float s[4];
#pragma unroll
  for (int j = 0; j < 4; j++) {
    float pf = bf2f((unsigned short)p4[j]);
    s[j] = kf[j] + pf;
    part += uf[j] * kf[j] + vf[j] * pf;
  }
  uint2 o;
  o.x = cvtpk(s[0], s[1]);
  o.y = cvtpk(s[2], s[3]);
  *(uint2*)(kp + (size_t)row * 64 + g * 4) = o;
#pragma unroll
  for (int sft = 1; sft < 16; sft <<= 1) part += __shfl_xor(part, sft, 64);
  if (g == 0) cb[row] = part;
}

__global__ __launch_bounds__(256, 8) void pack_mask(
    const int* __restrict__ m, unsigned long long* __restrict__ mb) {
  int word = blockIdx.x * 4 + (threadIdx.x >> 6);
  int lane = threadIdx.x & 63;
  int v = m[(size_t)(word >> 4) * 1024 + (word & 15) * 64 + lane];
  unsigned long long bal = __ballot(v != 0);
  if (lane == 0) mb[word] = bal;
}

// flash attn: scores = (q.kp + c)*0.125, exp2-domain softmax vs fixed ref M=24
// (slow path keeps full online-softmax for general masks), O = P.V
__global__ __launch_bounds__(256, 4) void attn_kernel(
    const unsigned short* __restrict__ qw, const unsigned short* __restrict__ kpw,
    const unsigned short* __restrict__ vtw, const float* __restrict__ cb,
    const unsigned long long* __restrict__ mbits, unsigned short* __restrict__ ow) {
  __shared__ alignas(16) char KPls[2][64 * 128];
  __shared__ alignas(16) char VTls[2][64 * 128];
  __shared__ alignas(16) char Pls[4][16 * 128];

  const int tid = threadIdx.x;
  const int lane = tid & 63, w = tid >> 6;
  const int lg = lane >> 4, lr = lane & 15;
  const int t0 = blockIdx.x * 64;
  const int bh = blockIdx.y;
  const int b = bh >> 3;
  const int h = bh & 7;
  const float NEG = -3.0e38f;
  const float SC = 0.125f * 1.44269504088896f;  // log2e folded in
  const float MREF = 24.0f;                     // fixed softmax reference

  const size_t qrow0 = (size_t)bh * 1024 + t0 + w * 16;
  bf16x8 qf[2];
#pragma unroll
  for (int ks = 0; ks < 2; ks++)
    qf[ks] = *(const bf16x8*)(qw + (qrow0 + lr) * 64 + ks * 32 + lg * 8);

  f32x4 oacc[4];
#pragma unroll
  for (int d = 0; d < 4; d++) oacc[d] = (f32x4)(0.f);
  float mrow[4], lsum[4];
#pragma unroll
  for (int r = 0; r < 4; r++) { mrow[r] = MREF; lsum[r] = 0.f; }

  auto stage = [&](int buf, int s0) {
    const size_t kr0 = (size_t)bh * 1024 + s0;
#pragma unroll
    for (int rep = 0; rep < 2; rep++) {
      int cid = rep * 256 + tid;
      int row = cid >> 3, c = cid & 7;
      gld16(kpw + (kr0 + row) * 64 + ((c ^ (row & 7)) << 3),
            KPls[buf] + ((rep * 256 + (w << 6)) << 4));
      gld16(vtw + ((size_t)bh * 64 + row) * 1024 + s0 + ((c ^ (row & 7)) << 3),
            VTls[buf] + ((rep * 256 + (w << 6)) << 4));
    }
  };

  stage(0, 0);
  __syncthreads();
  int cur = 0;
  for (int s0 = 0; s0 < 1024; s0 += 64) {
    if (s0 + 64 < 1024) stage(cur ^ 1, s0 + 64);

    f32x4 sacc[4];
    __builtin_amdgcn_s_setprio(1);
#pragma unroll
    for (int st = 0; st < 4; st++) {
      sacc[st] = (f32x4)(0.f);
#pragma unroll
      for (int ks = 0; ks < 2; ks++) {
        int row = st * 16 + lr;
        bf16x8 kf = *(const bf16x8*)(KPls[cur] + row * 128 +
                                     (((ks * 4 + lg) ^ (row & 7)) << 4));
        sacc[st] = __builtin_amdgcn_mfma_f32_16x16x32_bf16(qf[ks], kf, sacc[st], 0, 0, 0);
      }
    }
    __builtin_amdgcn_s_setprio(0);

    unsigned long long mb[4];
#pragma unroll
    for (int r = 0; r < 4; r++)
      mb[r] = mbits[((size_t)b * 1024 + (t0 + w * 16 + lg * 4 + r)) * 16 + (s0 >> 6)];
    float cv2[4];
#pragma unroll
    for (int st = 0; st < 4; st++)
      cv2[st] = cb[(size_t)bh * 1024 + s0 + st * 16 + lr] * SC;

    unsigned short pb[4][4];
    bool full = (mb[0] & mb[1] & mb[2] & mb[3]) == ~0ull;
    if (__all(full)) {
      // fast path: no masking, no max tracking, no rescale
#pragma unroll
      for (int st = 0; st < 4; st++)
#pragma unroll
        for (int r = 0; r < 4; r++) {
          float sv = fmaf(sacc[st][r], SC, cv2[st]);
          float p = exp2f(sv - mrow[r]);
          lsum[r] += p;
          pb[st][r] = cvt1(p);
        }
    } else {
      float sv[4][4];
#pragma unroll
      for (int st = 0; st < 4; st++)
#pragma unroll
        for (int r = 0; r < 4; r++) {
          float x = fmaf(sacc[st][r], SC, cv2[st]);
          sv[st][r] = ((mb[r] >> (st * 16 + lr)) & 1ull) ? x : NEG;
        }
      float scale[4];
#pragma unroll
      for (int r = 0; r < 4; r++) {
        float mx = fmaxf(fmaxf(sv[0][r], sv[1][r]), fmaxf(sv[2][r], sv[3][r]));
#pragma unroll
        for (int o = 1; o < 16; o <<= 1) mx = fmaxf(mx, __shfl_xor(mx, o, 64));
        float mn = fmaxf(mrow[r], mx);
        scale[r] = (mn == mrow[r]) ? 1.f : exp2f(mrow[r] - mn);
        mrow[r] = mn;
        lsum[r] *= scale[r];
      }
#pragma unroll
      for (int st = 0; st < 4; st++)
#pragma unroll
        for (int r = 0; r < 4; r++) {
          bool on = (mb[r] >> (st * 16 + lr)) & 1ull;
          float p = on ? exp2f(sv[st][r] - mrow[r]) : 0.f;
          lsum[r] += p;
          pb[st][r] = cvt1(p);
        }
#pragma unroll
      for (int d = 0; d < 4; d++)
#pragma unroll
        for (int r = 0; r < 4; r++) oacc[d][r] *= scale[r];
    }

#pragma unroll
    for (int st = 0; st < 4; st++)
#pragma unroll
      for (int r = 0; r < 4; r++) {
        int row = lg * 4 + r;
        *(unsigned short*)(Pls[w] + row * 128 +
                           (((st * 16 + lr) * 2) ^ ((row & 7) << 4))) = pb[st][r];
      }
    __builtin_amdgcn_s_setprio(1);
#pragma unroll
    for (int ks = 0; ks < 2; ks++) {
      bf16x8 pf = *(const bf16x8*)(Pls[w] + lr * 128 +
                                   (((ks * 4 + lg) ^ (lr & 7)) << 4));
#pragma unroll
      for (int d = 0; d < 4; d++) {
        int row = d * 16 + lr;
        bf16x8 vf = *(const bf16x8*)(VTls[cur] + row * 128 +
                                     (((ks * 4 + lg) ^ (row & 7)) << 4));
        oacc[d] = __builtin_amdgcn_mfma_f32_16x16x32_bf16(pf, vf, oacc[d], 0, 0, 0);
      }
    }
    __builtin_amdgcn_s_setprio(0);
    __syncthreads();
    cur ^= 1;
  }
  // reduce per-lane partial lsum across the 16 lanes of each row group
  float inv[4];
#pragma unroll
  for (int r = 0; r < 4; r++) {
    float s = lsum[r];
#pragma unroll
    for (int o = 1; o < 16; o <<= 1) s += __shfl_xor(s, o, 64);
    inv[r] = (s > 0.f) ? 1.f / s : 0.f;
  }
#pragma unroll
  for (int d = 0; d < 4; d++)
#pragma unroll
    for (int r = 0; r < 4; r++) {
      int t = t0 + w * 16 + lg * 4 + r;
      ow[((size_t)b * 1024 + t) * 512 + h * 64 + d * 16 + lr] = cvt1(oacc[d][r] * inv[r]);
    }
}

extern "C" void kernel_launch(void* const* d_in, const int* in_sizes, int n_in,
                              void* d_out, int out_size, void* d_ws, size_t ws_size,
                              hipStream_t stream) {
  const float* query = (const float*)d_in[0];
  const float* key = (const float*)d_in[1];
  const float* value = (const float*)d_in[2];
  const int* amask = (const int*)d_in[3];
  const float* pos = (const float*)d_in[4];
  const float* Wq = (const float*)d_in[5];
  const float* bq = (const float*)d_in[6];
  const float* Wk = (const float*)d_in[7];
  const float* bk = (const float*)d_in[8];
  const float* Wv = (const float*)d_in[9];
  const float* bv = (const float*)d_in[10];
  const float* Wpos = (const float*)d_in[11];
  const float* Wout = (const float*)d_in[12];
  const float* bout = (const float*)d_in[13];
  const float* pbu = (const float*)d_in[14];
  const float* pbv = (const float*)d_in[15];

  float* out = (float*)d_out;               // [8192,512] f32
  float* cache = out + (size_t)8192 * 512;  // [64,1024,128] f32

  char* ws = (char*)d_ws;
  unsigned short* ws_q = (unsigned short*)(ws);                     // 8.39 MB
  unsigned short* ws_kp = (unsigned short*)(ws + 8388608);          // 8.39 MB (p, then kp in-place)
  unsigned short* ws_vt = (unsigned short*)(ws + 16777216);         // 8.39 MB (V^T bf16)
  unsigned short* ws_o = (unsigned short*)(ws + 25165824);          // 8.39 MB (attn out)
  unsigned short* W4 = ws_o;                                        // 2.10 MB, dead before attn
  float* cbuf = (float*)(ws + 33554432);                            // 0.26 MB
  unsigned long long* mbits = (unsigned long long*)(ws + 33816576); // 1.05 MB
  unsigned short* Woutb = ws_q;                                     // reused after attn

  dim3 blk(256);
  prep_w<<<dim3(128, 4), blk, 0, stream>>>(Wq, Wk, Wv, Wpos, W4);
  gemm_bt<true><<<dim3(64, 8, 4), blk, 0, stream>>>(
      query, key, value, pos, W4, bq, bk, bv, 0, ws_q, cache, ws_vt, ws_kp, nullptr);
  fuse_kp<<<dim3(4096), blk, 0, stream>>>(cache, ws_kp, pbu, pbv, cbuf);
  pack_mask<<<dim3(32768), blk, 0, stream>>>(amask, mbits);
  attn_kernel<<<dim3(16, 64), blk, 0, stream>>>(ws_q, ws_kp, ws_vt, cbuf, mbits, ws_o);
  prep_w<<<dim3(128, 1), blk, 0, stream>>>(Wout, Wout, Wout, Wout, Woutb);
  gemm_bt<false><<<dim3(64, 8, 1), blk, 0, stream>>>(
      ws_o, nullptr, nullptr, nullptr, Woutb, bout, nullptr, nullptr, 4,
      nullptr, nullptr, nullptr, nullptr, out);
}

// Round 5
// 149.579 us; speedup vs baseline: 2.1981x; 1.0765x over previous
//
#include <hip/hip_runtime.h>

typedef __attribute__((ext_vector_type(8))) short bf16x8;
typedef __attribute__((ext_vector_type(4))) float f32x4;
typedef __attribute__((ext_vector_type(4))) unsigned short u16x4;

#define DEVFN static __device__ __forceinline__

// hardware packed f32->bf16 (RNE): lo -> low16, hi -> high16
DEVFN unsigned cvtpk(float lo, float hi) {
  unsigned r;
  asm("v_cvt_pk_bf16_f32 %0, %1, %2" : "=v"(r) : "v"(lo), "v"(hi));
  return r;
}
DEVFN unsigned short cvt1(float x) {
  unsigned r;
  asm("v_cvt_pk_bf16_f32 %0, %1, %1" : "=v"(r) : "v"(x));
  return (unsigned short)r;
}
DEVFN float bf2f(unsigned short s) { return __uint_as_float(((unsigned)s) << 16); }

// async 16B global->LDS. LDS dest must be wave-uniform base (HW adds lane*16).
DEVFN void gld16(const void* g, void* l) {
  __builtin_amdgcn_global_load_lds(
      (const __attribute__((address_space(1))) unsigned int*)g,
      (__attribute__((address_space(3))) unsigned int*)l, 16, 0, 0);
}

// convert 4 weight matrices f32->bf16 (or 1, grid.y=1)
__global__ __launch_bounds__(256, 8) void prep_w(
    const float* __restrict__ s0, const float* __restrict__ s1,
    const float* __restrict__ s2, const float* __restrict__ s3,
    unsigned short* __restrict__ dst) {
  const float* s = blockIdx.y == 0 ? s0 : blockIdx.y == 1 ? s1
                   : blockIdx.y == 2 ? s2 : s3;
  size_t base = (size_t)blockIdx.y * 262144;
  size_t idx = ((size_t)blockIdx.x * 256 + threadIdx.x) * 8;
  float4 a = *(const float4*)(s + idx);
  float4 b = *(const float4*)(s + idx + 4);
  uint4 o;
  o.x = cvtpk(a.x, a.y); o.y = cvtpk(a.z, a.w);
  o.z = cvtpk(b.x, b.y); o.w = cvtpk(b.z, b.w);
  *(uint4*)(dst + base + idx) = o;
}

// C = A (8192xK=512) * W^T (W N=512xK=512 row-major). Tile 128x64, BK=64,
// double-buffered LDS, prefetch-before-compute. LDS rows 128B; 16B chunk c of
// row r stored at chunk (c ^ (r&7)) -> conflict-free ds_read_b128.
// mode 0=Q 1=K 2=V 3=P (blockIdx.z), 4=OUT.
template <bool AF32>
__global__ __launch_bounds__(256, 3) void gemm_bt(
    const void* A0, const void* A1, const void* A2, const void* A3,
    const unsigned short* __restrict__ Wb, const float* b0, const float* b1,
    const float* b2, int mode_base,
    unsigned short* __restrict__ qout, float* __restrict__ cache,
    unsigned short* __restrict__ vtout, unsigned short* __restrict__ pout,
    float* __restrict__ fout) {
  __shared__ alignas(16) char Als[2][128 * 128];
  __shared__ alignas(16) char Bls[2][64 * 128];
  const int tid = threadIdx.x;
  const int lane = tid & 63, w = tid >> 6;
  const int wr = (w >> 1) * 64, wc = (w & 1) * 32;
  const int lg = lane >> 4, lr = lane & 15;
  const int m0 = blockIdx.x * 128, n0 = blockIdx.y * 64;
  const int mode = mode_base + blockIdx.z;
  const void* Ap = (mode == 1) ? A1 : (mode == 2) ? A2 : (mode == 3) ? A3 : A0;
  const unsigned short* Wp = Wb + (mode_base ? 0 : blockIdx.z * 262144);
  const float* bias = (mode == 0 || mode == 4) ? b0
                      : (mode == 1) ? b1 : (mode == 2) ? b2 : nullptr;

  auto stageA = [&](int buf, int k0) {
    if constexpr (AF32) {
      const float* Af = (const float*)Ap;
#pragma unroll
      for (int rep = 0; rep < 4; rep++) {
        int cid = rep * 256 + tid;
        int row = cid >> 3, c = cid & 7;
        const float* src = Af + (size_t)(m0 + row) * 512 + k0 + c * 8;
        float4 fa = *(const float4*)(src);
        float4 fb = *(const float4*)(src + 4);
        uint4 o;
        o.x = cvtpk(fa.x, fa.y); o.y = cvtpk(fa.z, fa.w);
        o.z = cvtpk(fb.x, fb.y); o.w = cvtpk(fb.z, fb.w);
        *(uint4*)(Als[buf] + row * 128 + ((c ^ (row & 7)) << 4)) = o;
      }
    } else {
      const unsigned short* Ab = (const unsigned short*)Ap;
#pragma unroll
      for (int rep = 0; rep < 4; rep++) {
        int cid = rep * 256 + tid;
        int row = cid >> 3, c = cid & 7;
        gld16(Ab + (size_t)(m0 + row) * 512 + k0 + ((c ^ (row & 7)) << 3),
              Als[buf] + ((rep * 256 + (w << 6)) << 4));
      }
    }
  };
  auto stageB = [&](int buf, int k0) {
#pragma unroll
    for (int rep = 0; rep < 2; rep++) {
      int cid = rep * 256 + tid;
      int row = cid >> 3, c = cid & 7;
      gld16(Wp + (size_t)(n0 + row) * 512 + k0 + ((c ^ (row & 7)) << 3),
            Bls[buf] + ((rep * 256 + (w << 6)) << 4));
    }
  };

  f32x4 acc[4][2];
#pragma unroll
  for (int i = 0; i < 4; i++)
#pragma unroll
    for (int j = 0; j < 2; j++) acc[i][j] = (f32x4)(0.f);

  stageA(0, 0);
  stageB(0, 0);
  __syncthreads();
  int cur = 0;
  for (int k0 = 0; k0 < 512; k0 += 64) {
    if (k0 + 64 < 512) { stageA(cur ^ 1, k0 + 64); stageB(cur ^ 1, k0 + 64); }
#pragma unroll
    for (int ks = 0; ks < 2; ks++) {
      bf16x8 af[4], bfr[2];
#pragma unroll
      for (int i = 0; i < 4; i++) {
        int row = wr + i * 16 + lr;
        af[i] = *(const bf16x8*)(Als[cur] + row * 128 + (((ks * 4 + lg) ^ (row & 7)) << 4));
      }
#pragma unroll
      for (int j = 0; j < 2; j++) {
        int row = wc + j * 16 + lr;
        bfr[j] = *(const bf16x8*)(Bls[cur] + row * 128 + (((ks * 4 + lg) ^ (row & 7)) << 4));
      }
#pragma unroll
      for (int i = 0; i < 4; i++)
#pragma unroll
        for (int j = 0; j < 2; j++)
          acc[i][j] = __builtin_amdgcn_mfma_f32_16x16x32_bf16(af[i], bfr[j],
                                                              acc[i][j], 0, 0, 0);
    }
    __syncthreads();
    cur ^= 1;
  }

#pragma unroll
  for (int i = 0; i < 4; i++) {
#pragma unroll
    for (int j = 0; j < 2; j++) {
      int colg = n0 + wc + j * 16 + lr;
      float bc = bias ? bias[colg] : 0.f;
      if (mode == 4) {
#pragma unroll
        for (int r = 0; r < 4; r++) {
          int rowg = m0 + wr + i * 16 + lg * 4 + r;
          fout[(size_t)rowg * 512 + colg] = acc[i][j][r] + bc;
        }
      } else {
        int rbase = m0 + wr + i * 16 + lg * 4;
        int b = rbase >> 10, t = rbase & 1023, h = colg >> 6, dk = colg & 63;
        size_t bht = (size_t)(b * 8 + h) * 1024 + t;
        if (mode == 0) {
#pragma unroll
          for (int r = 0; r < 4; r++) qout[(bht + r) * 64 + dk] = cvt1(acc[i][j][r] + bc);
        } else if (mode == 1) {
#pragma unroll
          for (int r = 0; r < 4; r++) cache[(bht + r) * 128 + dk] = acc[i][j][r] + bc;
        } else if (mode == 3) {
#pragma unroll
          for (int r = 0; r < 4; r++) pout[(bht + r) * 64 + dk] = cvt1(acc[i][j][r]);
        } else {
          float vv[4];
#pragma unroll
          for (int r = 0; r < 4; r++) {
            vv[r] = acc[i][j][r] + bc;
            cache[(bht + r) * 128 + 64 + dk] = vv[r];
          }
          uint2 pv;
          pv.x = cvtpk(vv[0], vv[1]);
          pv.y = cvtpk(vv[2], vv[3]);
          *(uint2*)(vtout + ((size_t)(b * 8 + h) * 64 + dk) * 1024 + t) = pv;
        }
      }
    }
  }
}

// in-place: p (bf16, in kp buffer) + k (f32 cache) -> kp bf16; c = u.k + v.p
__global__ __launch_bounds__(256, 4) void fuse_kp(
    const float* __restrict__ kcache, unsigned short* __restrict__ kp,
    const float* __restrict__ ub, const float* __restrict__ vb,
    float* __restrict__ cb) {
  int tid = threadIdx.x;
  int row = blockIdx.x * 16 + (tid >> 4);
  int g = tid & 15;
  int h = (row >> 10) & 7;
  float4 k4 = *(const float4*)(kcache + (size_t)row * 128 + g * 4);
  u16x4 p4 = *(const u16x4*)(kp + (size_t)row * 64 + g * 4);
  float4 uu = *(const float4*)(ub + h * 64 + g * 4);
  float4 vv = *(const float4*)(vb + h * 64 + g * 4);
  float kf[4] = {k4.x, k4.y, k4.z, k4.w};
  float uf[4] = {uu.x, uu.y, uu.z, uu.w};
  float vf[4] = {vv.x, vv.y, vv.z, vv.w};
  float part = 0.f;
  float s[4];
#pragma unroll
  for (int j = 0; j < 4; j++) {
    float pf = bf2f((unsigned short)p4[j]);
    s[j] = kf[j] + pf;
    part += uf[j] * kf[j] + vf[j] * pf;
  }
  uint2 o;
  o.x = cvtpk(s[0], s[1]);
  o.y = cvtpk(s[2], s[3]);
  *(uint2*)(kp + (size_t)row * 64 + g * 4) = o;
#pragma unroll
  for (int sft = 1; sft < 16; sft <<= 1) part += __shfl_xor(part, sft, 64);
  if (g == 0) cb[row] = part;
}

__global__ __launch_bounds__(256, 8) void pack_mask(
    const int* __restrict__ m, unsigned long long* __restrict__ mb) {
  int word = blockIdx.x * 4 + (threadIdx.x >> 6);
  int lane = threadIdx.x & 63;
  int v = m[(size_t)(word >> 4) * 1024 + (word & 15) * 64 + lane];
  unsigned long long bal = __ballot(v != 0);
  if (lane == 0) mb[word] = bal;
}

// flash attn: scores = (q.kp + c)*0.125, exp2-domain softmax vs fixed ref M=24
// (slow path keeps full online-softmax for general masks), O = P.V
// 8 waves x 16 q-rows = 128 q-rows per block; KVBLK=64.
__global__ __launch_bounds__(512, 2) void attn_kernel(
    const unsigned short* __restrict__ qw, const unsigned short* __restrict__ kpw,
    const unsigned short* __restrict__ vtw, const float* __restrict__ cb,
    const unsigned long long* __restrict__ mbits, unsigned short* __restrict__ ow) {
  __shared__ alignas(16) char KPls[2][64 * 128];
  __shared__ alignas(16) char VTls[2][64 * 128];
  __shared__ alignas(16) char Pls[8][16 * 128];

  const int tid = threadIdx.x;
  const int lane = tid & 63, w = tid >> 6;
  const int lg = lane >> 4, lr = lane & 15;
  const int t0 = blockIdx.x * 128;
  const int bh = blockIdx.y;
  const int b = bh >> 3;
  const int h = bh & 7;
  const float NEG = -3.0e38f;
  const float SC = 0.125f * 1.44269504088896f;  // log2e folded in
  const float MREF = 24.0f;                     // fixed softmax reference

  const size_t qrow0 = (size_t)bh * 1024 + t0 + w * 16;
  bf16x8 qf[2];
#pragma unroll
  for (int ks = 0; ks < 2; ks++)
    qf[ks] = *(const bf16x8*)(qw + (qrow0 + lr) * 64 + ks * 32 + lg * 8);

  f32x4 oacc[4];
#pragma unroll
  for (int d = 0; d < 4; d++) oacc[d] = (f32x4)(0.f);
  float mrow[4], lsum[4];
#pragma unroll
  for (int r = 0; r < 4; r++) { mrow[r] = MREF; lsum[r] = 0.f; }

  // 512 threads stage 64 rows x 128B per buffer in one pass each
  auto stage = [&](int buf, int s0) {
    const size_t kr0 = (size_t)bh * 1024 + s0;
    int row = tid >> 3, c = tid & 7;
    gld16(kpw + (kr0 + row) * 64 + ((c ^ (row & 7)) << 3),
          KPls[buf] + ((w << 6) << 4));
    gld16(vtw + ((size_t)bh * 64 + row) * 1024 + s0 + ((c ^ (row & 7)) << 3),
          VTls[buf] + ((w << 6) << 4));
  };

  stage(0, 0);
  __syncthreads();
  int cur = 0;
  for (int s0 = 0; s0 < 1024; s0 += 64) {
    if (s0 + 64 < 1024) stage(cur ^ 1, s0 + 64);

    f32x4 sacc[4];
    __builtin_amdgcn_s_setprio(1);
#pragma unroll
    for (int st = 0; st < 4; st++) {
      sacc[st] = (f32x4)(0.f);
#pragma unroll
      for (int ks = 0; ks < 2; ks++) {
        int row = st * 16 + lr;
        bf16x8 kf = *(const bf16x8*)(KPls[cur] + row * 128 +
                                     (((ks * 4 + lg) ^ (row & 7)) << 4));
        sacc[st] = __builtin_amdgcn_mfma_f32_16x16x32_bf16(qf[ks], kf, sacc[st], 0, 0, 0);
      }
    }
    __builtin_amdgcn_s_setprio(0);

    unsigned long long mb[4];
#pragma unroll
    for (int r = 0; r < 4; r++)
      mb[r] = mbits[((size_t)b * 1024 + (t0 + w * 16 + lg * 4 + r)) * 16 + (s0 >> 6)];
    float cv2[4];
#pragma unroll
    for (int st = 0; st < 4; st++)
      cv2[st] = cb[(size_t)bh * 1024 + s0 + st * 16 + lr] * SC;

    unsigned short pb[4][4];
    bool full = (mb[0] & mb[1] & mb[2] & mb[3]) == ~0ull;
    if (__all(full)) {
      // fast path: no masking, no max tracking, no rescale
#pragma unroll
      for (int st = 0; st < 4; st++)
#pragma unroll
        for (int r = 0; r < 4; r++) {
          float sv = fmaf(sacc[st][r], SC, cv2[st]);
          float p = exp2f(sv - mrow[r]);
          lsum[r] += p;
          pb[st][r] = cvt1(p);
        }
    } else {
      float sv[4][4];
#pragma unroll
      for (int st = 0; st < 4; st++)
#pragma unroll
        for (int r = 0; r < 4; r++) {
          float x = fmaf(sacc[st][r], SC, cv2[st]);
          sv[st][r] = ((mb[r] >> (st * 16 + lr)) & 1ull) ? x : NEG;
        }
      float scale[4];
#pragma unroll
      for (int r = 0; r < 4; r++) {
        float mx = fmaxf(fmaxf(sv[0][r], sv[1][r]), fmaxf(sv[2][r], sv[3][r]));
#pragma unroll
        for (int o = 1; o < 16; o <<= 1) mx = fmaxf(mx, __shfl_xor(mx, o, 64));
        float mn = fmaxf(mrow[r], mx);
        scale[r] = (mn == mrow[r]) ? 1.f : exp2f(mrow[r] - mn);
        mrow[r] = mn;
        lsum[r] *= scale[r];
      }
#pragma unroll
      for (int st = 0; st < 4; st++)
#pragma unroll
        for (int r = 0; r < 4; r++) {
          bool on = (mb[r] >> (st * 16 + lr)) & 1ull;
          float p = on ? exp2f(sv[st][r] - mrow[r]) : 0.f;
          lsum[r] += p;
          pb[st][r] = cvt1(p);
        }
#pragma unroll
      for (int d = 0; d < 4; d++)
#pragma unroll
        for (int r = 0; r < 4; r++) oacc[d][r] *= scale[r];
    }

#pragma unroll
    for (int st = 0; st < 4; st++)
#pragma unroll
      for (int r = 0; r < 4; r++) {
        int row = lg * 4 + r;
        *(unsigned short*)(Pls[w] + row * 128 +
                           (((st * 16 + lr) * 2) ^ ((row & 7) << 4))) = pb[st][r];
      }
    __builtin_amdgcn_s_setprio(1);
#pragma unroll
    for (int ks = 0; ks < 2; ks++) {
      bf16x8 pf = *(const bf16x8*)(Pls[w] + lr * 128 +
                                   (((ks * 4 + lg) ^ (lr & 7)) << 4));
#pragma unroll
      for (int d = 0; d < 4; d++) {
        int row = d * 16 + lr;
        bf16x8 vf = *(const bf16x8*)(VTls[cur] + row * 128 +
                                     (((ks * 4 + lg) ^ (row & 7)) << 4));
        oacc[d] = __builtin_amdgcn_mfma_f32_16x16x32_bf16(pf, vf, oacc[d], 0, 0, 0);
      }
    }
    __builtin_amdgcn_s_setprio(0);
    __syncthreads();
    cur ^= 1;
  }
  // reduce per-lane partial lsum across the 16 lanes of each row group
  float inv[4];
#pragma unroll
  for (int r = 0; r < 4; r++) {
    float s = lsum[r];
#pragma unroll
    for (int o = 1; o < 16; o <<= 1) s += __shfl_xor(s, o, 64);
    inv[r] = (s > 0.f) ? 1.f / s : 0.f;
  }
#pragma unroll
  for (int d = 0; d < 4; d++)
#pragma unroll
    for (int r = 0; r < 4; r++) {
      int t = t0 + w * 16 + lg * 4 + r;
      ow[((size_t)b * 1024 + t) * 512 + h * 64 + d * 16 + lr] = cvt1(oacc[d][r] * inv[r]);
    }
}

extern "C" void kernel_launch(void* const* d_in, const int* in_sizes, int n_in,
                              void* d_out, int out_size, void* d_ws, size_t ws_size,
                              hipStream_t stream) {
  const float* query = (const float*)d_in[0];
  const float* key = (const float*)d_in[1];
  const float* value = (const float*)d_in[2];
  const int* amask = (const int*)d_in[3];
  const float* pos = (const float*)d_in[4];
  const float* Wq = (const float*)d_in[5];
  const float* bq = (const float*)d_in[6];
  const float* Wk = (const float*)d_in[7];
  const float* bk = (const float*)d_in[8];
  const float* Wv = (const float*)d_in[9];
  const float* bv = (const float*)d_in[10];
  const float* Wpos = (const float*)d_in[11];
  const float* Wout = (const float*)d_in[12];
  const float* bout = (const float*)d_in[13];
  const float* pbu = (const float*)d_in[14];
  const float* pbv = (const float*)d_in[15];

  float* out = (float*)d_out;               // [8192,512] f32
  float* cache = out + (size_t)8192 * 512;  // [64,1024,128] f32

  char* ws = (char*)d_ws;
  unsigned short* ws_q = (unsigned short*)(ws);                     // 8.39 MB
  unsigned short* ws_kp = (unsigned short*)(ws + 8388608);          // 8.39 MB (p, then kp in-place)
  unsigned short* ws_vt = (unsigned short*)(ws + 16777216);         // 8.39 MB (V^T bf16)
  unsigned short* ws_o = (unsigned short*)(ws + 25165824);          // 8.39 MB (attn out)
  unsigned short* W4 = ws_o;                                        // 2.10 MB, dead before attn
  float* cbuf = (float*)(ws + 33554432);                            // 0.26 MB
  unsigned long long* mbits = (unsigned long long*)(ws + 33816576); // 1.05 MB
  unsigned short* Woutb = ws_q;                                     // reused after attn

  dim3 blk(256);
  prep_w<<<dim3(128, 4), blk, 0, stream>>>(Wq, Wk, Wv, Wpos, W4);
  gemm_bt<true><<<dim3(64, 8, 4), blk, 0, stream>>>(
      query, key, value, pos, W4, bq, bk, bv, 0, ws_q, cache, ws_vt, ws_kp, nullptr);
  fuse_kp<<<dim3(4096), blk, 0, stream>>>(cache, ws_kp, pbu, pbv, cbuf);
  pack_mask<<<dim3(32768), blk, 0, stream>>>(amask, mbits);
  attn_kernel<<<dim3(8, 64), dim3(512), 0, stream>>>(ws_q, ws_kp, ws_vt, cbuf, mbits, ws_o);
  prep_w<<<dim3(128, 1), blk, 0, stream>>>(Wout, Wout, Wout, Wout, Woutb);
  gemm_bt<false><<<dim3(64, 8, 1), blk, 0, stream>>>(
      ws_o, nullptr, nullptr, nullptr, Woutb, bout, nullptr, nullptr, 4,
      nullptr, nullptr, nullptr, nullptr, out);
}

// Round 6
// 143.719 us; speedup vs baseline: 2.2877x; 1.0408x over previous
//
#include <hip/hip_runtime.h>

typedef __attribute__((ext_vector_type(8))) short bf16x8;
typedef __attribute__((ext_vector_type(4))) float f32x4;
typedef __attribute__((ext_vector_type(4))) unsigned short u16x4;

#define DEVFN static __device__ __forceinline__

// hardware packed f32->bf16 (RNE): lo -> low16, hi -> high16
DEVFN unsigned cvtpk(float lo, float hi) {
  unsigned r;
  asm("v_cvt_pk_bf16_f32 %0, %1, %2" : "=v"(r) : "v"(lo), "v"(hi));
  return r;
}
DEVFN unsigned short cvt1(float x) {
  unsigned r;
  asm("v_cvt_pk_bf16_f32 %0, %1, %1" : "=v"(r) : "v"(x));
  return (unsigned short)r;
}
DEVFN float fexp2(float x) {  // raw v_exp_f32 (2^x), no libm fixups
  float r;
  asm("v_exp_f32 %0, %1" : "=v"(r) : "v"(x));
  return r;
}
DEVFN float bf2f(unsigned short s) { return __uint_as_float(((unsigned)s) << 16); }

// async 16B global->LDS. LDS dest must be wave-uniform base (HW adds lane*16).
DEVFN void gld16(const void* g, void* l) {
  __builtin_amdgcn_global_load_lds(
      (const __attribute__((address_space(1))) unsigned int*)g,
      (__attribute__((address_space(3))) unsigned int*)l, 16, 0, 0);
}

// convert 4 weight matrices f32->bf16 (or 1, grid.y=1)
__global__ __launch_bounds__(256, 8) void prep_w(
    const float* __restrict__ s0, const float* __restrict__ s1,
    const float* __restrict__ s2, const float* __restrict__ s3,
    unsigned short* __restrict__ dst) {
  const float* s = blockIdx.y == 0 ? s0 : blockIdx.y == 1 ? s1
                   : blockIdx.y == 2 ? s2 : s3;
  size_t base = (size_t)blockIdx.y * 262144;
  size_t idx = ((size_t)blockIdx.x * 256 + threadIdx.x) * 8;
  float4 a = *(const float4*)(s + idx);
  float4 b = *(const float4*)(s + idx + 4);
  uint4 o;
  o.x = cvtpk(a.x, a.y); o.y = cvtpk(a.z, a.w);
  o.z = cvtpk(b.x, b.y); o.w = cvtpk(b.z, b.w);
  *(uint4*)(dst + base + idx) = o;
}

// C = A (8192xK=512) * W^T (W N=512xK=512 row-major). Tile 128x64, BK=64,
// double-buffered LDS. A-side (f32): T14 async-split — loads to regs before
// compute, cvt+ds_write after. LDS rows 128B; chunk c of row r at (c^(r&7)).
// mode 0=Q 1=K 2=V 3=P (blockIdx.z), 4=OUT.
template <bool AF32>
__global__ __launch_bounds__(256, 3) void gemm_bt(
    const void* A0, const void* A1, const void* A2, const void* A3,
    const unsigned short* __restrict__ Wb, const float* b0, const float* b1,
    const float* b2, int mode_base,
    unsigned short* __restrict__ qout, float* __restrict__ cache,
    unsigned short* __restrict__ vtout, unsigned short* __restrict__ pout,
    float* __restrict__ fout) {
  __shared__ alignas(16) char Als[2][128 * 128];
  __shared__ alignas(16) char Bls[2][64 * 128];
  const int tid = threadIdx.x;
  const int lane = tid & 63, w = tid >> 6;
  const int wr = (w >> 1) * 64, wc = (w & 1) * 32;
  const int lg = lane >> 4, lr = lane & 15;
  const int m0 = blockIdx.x * 128, n0 = blockIdx.y * 64;
  const int mode = mode_base + blockIdx.z;
  const void* Ap = (mode == 1) ? A1 : (mode == 2) ? A2 : (mode == 3) ? A3 : A0;
  const unsigned short* Wp = Wb + (mode_base ? 0 : blockIdx.z * 262144);
  const float* bias = (mode == 0 || mode == 4) ? b0
                      : (mode == 1) ? b1 : (mode == 2) ? b2 : nullptr;

  float4 ra[8];
  auto loadA = [&](int k0) {
    const float* Af = (const float*)Ap;
#pragma unroll
    for (int rep = 0; rep < 4; rep++) {
      int cid = rep * 256 + tid;
      int row = cid >> 3, c = cid & 7;
      const float* src = Af + (size_t)(m0 + row) * 512 + k0 + c * 8;
      ra[rep * 2] = *(const float4*)(src);
      ra[rep * 2 + 1] = *(const float4*)(src + 4);
    }
  };
  auto writeA = [&](int buf) {
#pragma unroll
    for (int rep = 0; rep < 4; rep++) {
      int cid = rep * 256 + tid;
      int row = cid >> 3, c = cid & 7;
      uint4 o;
      o.x = cvtpk(ra[rep * 2].x, ra[rep * 2].y);
      o.y = cvtpk(ra[rep * 2].z, ra[rep * 2].w);
      o.z = cvtpk(ra[rep * 2 + 1].x, ra[rep * 2 + 1].y);
      o.w = cvtpk(ra[rep * 2 + 1].z, ra[rep * 2 + 1].w);
      *(uint4*)(Als[buf] + row * 128 + ((c ^ (row & 7)) << 4)) = o;
    }
  };
  auto stageA_lds = [&](int buf, int k0) {  // bf16 A: direct async to LDS
    const unsigned short* Ab = (const unsigned short*)Ap;
#pragma unroll
    for (int rep = 0; rep < 4; rep++) {
      int cid = rep * 256 + tid;
      int row = cid >> 3, c = cid & 7;
      gld16(Ab + (size_t)(m0 + row) * 512 + k0 + ((c ^ (row & 7)) << 3),
            Als[buf] + ((rep * 256 + (w << 6)) << 4));
    }
  };
  auto stageB = [&](int buf, int k0) {
#pragma unroll
    for (int rep = 0; rep < 2; rep++) {
      int cid = rep * 256 + tid;
      int row = cid >> 3, c = cid & 7;
      gld16(Wp + (size_t)(n0 + row) * 512 + k0 + ((c ^ (row & 7)) << 3),
            Bls[buf] + ((rep * 256 + (w << 6)) << 4));
    }
  };

  f32x4 acc[4][2];
#pragma unroll
  for (int i = 0; i < 4; i++)
#pragma unroll
    for (int j = 0; j < 2; j++) acc[i][j] = (f32x4)(0.f);

  if constexpr (AF32) { loadA(0); writeA(0); } else { stageA_lds(0, 0); }
  stageB(0, 0);
  __syncthreads();
  int cur = 0;
  for (int k0 = 0; k0 < 512; k0 += 64) {
    bool more = (k0 + 64 < 512);
    if (more) {
      if constexpr (AF32) loadA(k0 + 64); else stageA_lds(cur ^ 1, k0 + 64);
      stageB(cur ^ 1, k0 + 64);
    }
#pragma unroll
    for (int ks = 0; ks < 2; ks++) {
      bf16x8 af[4], bfr[2];
#pragma unroll
      for (int i = 0; i < 4; i++) {
        int row = wr + i * 16 + lr;
        af[i] = *(const bf16x8*)(Als[cur] + row * 128 + (((ks * 4 + lg) ^ (row & 7)) << 4));
      }
#pragma unroll
      for (int j = 0; j < 2; j++) {
        int row = wc + j * 16 + lr;
        bfr[j] = *(const bf16x8*)(Bls[cur] + row * 128 + (((ks * 4 + lg) ^ (row & 7)) << 4));
      }
#pragma unroll
      for (int i = 0; i < 4; i++)
#pragma unroll
        for (int j = 0; j < 2; j++)
          acc[i][j] = __builtin_amdgcn_mfma_f32_16x16x32_bf16(af[i], bfr[j],
                                                              acc[i][j], 0, 0, 0);
    }
    if (more) { if constexpr (AF32) writeA(cur ^ 1); }
    __syncthreads();
    cur ^= 1;
  }

#pragma unroll
  for (int i = 0; i < 4; i++) {
#pragma unroll
    for (int j = 0; j < 2; j++) {
      int colg = n0 + wc + j * 16 + lr;
      float bc = bias ? bias[colg] : 0.f;
      if (mode == 4) {
#pragma unroll
        for (int r = 0; r < 4; r++) {
          int rowg = m0 + wr + i * 16 + lg * 4 + r;
          fout[(size_t)rowg * 512 + colg] = acc[i][j][r] + bc;
        }
      } else {
        int rbase = m0 + wr + i * 16 + lg * 4;
        int b = rbase >> 10, t = rbase & 1023, h = colg >> 6, dk = colg & 63;
        size_t bht = (size_t)(b * 8 + h) * 1024 + t;
        if (mode == 0) {
#pragma unroll
          for (int r = 0; r < 4; r++) qout[(bht + r) * 64 + dk] = cvt1(acc[i][j][r] + bc);
        } else if (mode == 1) {
#pragma unroll
          for (int r = 0; r < 4; r++) cache[(bht + r) * 128 + dk] = acc[i][j][r] + bc;
        } else if (mode == 3) {
#pragma unroll
          for (int r = 0; r < 4; r++) pout[(bht + r) * 64 + dk] = cvt1(acc[i][j][r]);
        } else {
          float vv[4];
#pragma unroll
          for (int r = 0; r < 4; r++) {
            vv[r] = acc[i][j][r] + bc;
            cache[(bht + r) * 128 + 64 + dk] = vv[r];
          }
          uint2 pv;
          pv.x = cvtpk(vv[0], vv[1]);
          pv.y = cvtpk(vv[2], vv[3]);
          *(uint2*)(vtout + ((size_t)(b * 8 + h) * 64 + dk) * 1024 + t) = pv;
        }
      }
    }
  }
}

// in-place: p (bf16, in kp buffer) + k (f32 cache) -> kp bf16; c = u.k + v.p
__global__ __launch_bounds__(256, 4) void fuse_kp(
    const float* __restrict__ kcache, unsigned short* __restrict__ kp,
    const float* __restrict__ ub, const float* __restrict__ vb,
    float* __restrict__ cb) {
  int tid = threadIdx.x;
  int row = blockIdx.x * 16 + (tid >> 4);
  int g = tid & 15;
  int h = (row >> 10) & 7;
  float4 k4 = *(const float4*)(kcache + (size_t)row * 128 + g * 4);
  u16x4 p4 = *(const u16x4*)(kp + (size_t)row * 64 + g * 4);
  float4 uu = *(const float4*)(ub + h * 64 + g * 4);
  float4 vv = *(const float4*)(vb + h * 64 + g * 4);
  float kf[4] = {k4.x, k4.y, k4.z, k4.w};
  float uf[4] = {uu.x, uu.y, uu.z, uu.w};
  float vf[4] = {vv.x, vv.y, vv.z, vv.w};
  float part = 0.f;
  float s[4];
#pragma unroll
  for (int j = 0; j < 4; j++) {
    float pf = bf2f((unsigned short)p4[j]);
    s[j] = kf[j] + pf;
    part += uf[j] * kf[j] + vf[j] * pf;
  }
  uint2 o;
  o.x = cvtpk(s[0], s[1]);
  o.y = cvtpk(s[2], s[3]);
  *(uint2*)(kp + (size_t)row * 64 + g * 4) = o;
#pragma unroll
  for (int sft = 1; sft < 16; sft <<= 1) part += __shfl_xor(part, sft, 64);
  if (g == 0) cb[row] = part;
}

__global__ __launch_bounds__(256, 8) void pack_mask(
    const int* __restrict__ m, unsigned long long* __restrict__ mb) {
  int word = blockIdx.x * 4 + (threadIdx.x >> 6);
  int lane = threadIdx.x & 63;
  int v = m[(size_t)(word >> 4) * 1024 + (word & 15) * 64 + lane];
  unsigned long long bal = __ballot(v != 0);
  if (lane == 0) mb[word] = bal;
}

// flash attn: scores = (q.kp + c)*0.125, exp2-domain softmax vs fixed ref M=24
// (slow path keeps full online-softmax for general masks), O = P.V
// 8 waves x 16 q-rows = 128 q-rows per block; KVBLK=64.
// 1D grid 512, XCD-swizzled: XCD x hosts bh in [8x,8x+8) -> per-XCD KV fits L2.
__global__ __launch_bounds__(512, 2) void attn_kernel(
    const unsigned short* __restrict__ qw, const unsigned short* __restrict__ kpw,
    const unsigned short* __restrict__ vtw, const float* __restrict__ cb,
    const unsigned long long* __restrict__ mbits, unsigned short* __restrict__ ow) {
  __shared__ alignas(16) char KPls[2][64 * 128];
  __shared__ alignas(16) char VTls[2][64 * 128];
  __shared__ alignas(16) char Pls[8][16 * 128];

  const int tid = threadIdx.x;
  const int lane = tid & 63, w = tid >> 6;
  const int lg = lane >> 4, lr = lane & 15;
  // XCD-aware decomposition of the 512 blocks (8 q-blocks x 64 bh)
  const int l = blockIdx.x;
  const int bh = (l & 7) * 8 + ((l >> 3) >> 3);
  const int t0 = ((l >> 3) & 7) * 128;
  const int b = bh >> 3;
  const int h = bh & 7;
  const float NEG = -3.0e38f;
  const float SC = 0.125f * 1.44269504088896f;  // log2e folded in
  const float MREF = 24.0f;                     // fixed softmax reference

  const size_t qrow0 = (size_t)bh * 1024 + t0 + w * 16;
  bf16x8 qf[2];
#pragma unroll
  for (int ks = 0; ks < 2; ks++)
    qf[ks] = *(const bf16x8*)(qw + (qrow0 + lr) * 64 + ks * 32 + lg * 8);

  f32x4 oacc[4];
#pragma unroll
  for (int d = 0; d < 4; d++) oacc[d] = (f32x4)(0.f);
  float mrow[4], lsum[4];
#pragma unroll
  for (int r = 0; r < 4; r++) { mrow[r] = MREF; lsum[r] = 0.f; }

  // 512 threads stage 64 rows x 128B per buffer in one pass each
  auto stage = [&](int buf, int s0) {
    const size_t kr0 = (size_t)bh * 1024 + s0;
    int row = tid >> 3, c = tid & 7;
    gld16(kpw + (kr0 + row) * 64 + ((c ^ (row & 7)) << 3),
          KPls[buf] + ((w << 6) << 4));
    gld16(vtw + ((size_t)bh * 64 + row) * 1024 + s0 + ((c ^ (row & 7)) << 3),
          VTls[buf] + ((w << 6) << 4));
  };

  stage(0, 0);
  __syncthreads();
  int cur = 0;
  for (int s0 = 0; s0 < 1024; s0 += 64) {
    if (s0 + 64 < 1024) stage(cur ^ 1, s0 + 64);

    f32x4 sacc[4];
    __builtin_amdgcn_s_setprio(1);
#pragma unroll
    for (int st = 0; st < 4; st++) {
      sacc[st] = (f32x4)(0.f);
#pragma unroll
      for (int ks = 0; ks < 2; ks++) {
        int row = st * 16 + lr;
        bf16x8 kf = *(const bf16x8*)(KPls[cur] + row * 128 +
                                     (((ks * 4 + lg) ^ (row & 7)) << 4));
        sacc[st] = __builtin_amdgcn_mfma_f32_16x16x32_bf16(qf[ks], kf, sacc[st], 0, 0, 0);
      }
    }
    __builtin_amdgcn_s_setprio(0);

    unsigned long long mb[4];
#pragma unroll
    for (int r = 0; r < 4; r++)
      mb[r] = mbits[((size_t)b * 1024 + (t0 + w * 16 + lg * 4 + r)) * 16 + (s0 >> 6)];
    float cv2[4];
#pragma unroll
    for (int st = 0; st < 4; st++)
      cv2[st] = cb[(size_t)bh * 1024 + s0 + st * 16 + lr] * SC;

    unsigned short pb[4][4];
    bool full = (mb[0] & mb[1] & mb[2] & mb[3]) == ~0ull;
    if (__all(full)) {
      // fast path: no masking, no max tracking, no rescale
#pragma unroll
      for (int st = 0; st < 4; st++)
#pragma unroll
        for (int r = 0; r < 4; r++) {
          float sv = fmaf(sacc[st][r], SC, cv2[st]);
          float p = fexp2(sv - mrow[r]);
          lsum[r] += p;
          pb[st][r] = cvt1(p);
        }
    } else {
      float sv[4][4];
#pragma unroll
      for (int st = 0; st < 4; st++)
#pragma unroll
        for (int r = 0; r < 4; r++) {
          float x = fmaf(sacc[st][r], SC, cv2[st]);
          sv[st][r] = ((mb[r] >> (st * 16 + lr)) & 1ull) ? x : NEG;
        }
      float scale[4];
#pragma unroll
      for (int r = 0; r < 4; r++) {
        float mx = fmaxf(fmaxf(sv[0][r], sv[1][r]), fmaxf(sv[2][r], sv[3][r]));
#pragma unroll
        for (int o = 1; o < 16; o <<= 1) mx = fmaxf(mx, __shfl_xor(mx, o, 64));
        float mn = fmaxf(mrow[r], mx);
        scale[r] = (mn == mrow[r]) ? 1.f : fexp2(mrow[r] - mn);
        mrow[r] = mn;
        lsum[r] *= scale[r];
      }
#pragma unroll
      for (int st = 0; st < 4; st++)
#pragma unroll
        for (int r = 0; r < 4; r++) {
          bool on = (mb[r] >> (st * 16 + lr)) & 1ull;
          float p = on ? fexp2(sv[st][r] - mrow[r]) : 0.f;
          lsum[r] += p;
          pb[st][r] = cvt1(p);
        }
#pragma unroll
      for (int d = 0; d < 4; d++)
#pragma unroll
        for (int r = 0; r < 4; r++) oacc[d][r] *= scale[r];
    }

#pragma unroll
    for (int st = 0; st < 4; st++)
#pragma unroll
      for (int r = 0; r < 4; r++) {
        int row = lg * 4 + r;
        *(unsigned short*)(Pls[w] + row * 128 +
                           (((st * 16 + lr) * 2) ^ ((row & 7) << 4))) = pb[st][r];
      }
    __builtin_amdgcn_s_setprio(1);
#pragma unroll
    for (int ks = 0; ks < 2; ks++) {
      bf16x8 pf = *(const bf16x8*)(Pls[w] + lr * 128 +
                                   (((ks * 4 + lg) ^ (lr & 7)) << 4));
#pragma unroll
      for (int d = 0; d < 4; d++) {
        int row = d * 16 + lr;
        bf16x8 vf = *(const bf16x8*)(VTls[cur] + row * 128 +
                                     (((ks * 4 + lg) ^ (row & 7)) << 4));
        oacc[d] = __builtin_amdgcn_mfma_f32_16x16x32_bf16(pf, vf, oacc[d], 0, 0, 0);
      }
    }
    __builtin_amdgcn_s_setprio(0);
    __syncthreads();
    cur ^= 1;
  }
  // reduce per-lane partial lsum across the 16 lanes of each row group
  float inv[4];
#pragma unroll
  for (int r = 0; r < 4; r++) {
    float s = lsum[r];
#pragma unroll
    for (int o = 1; o < 16; o <<= 1) s += __shfl_xor(s, o, 64);
    inv[r] = (s > 0.f) ? 1.f / s : 0.f;
  }
#pragma unroll
  for (int d = 0; d < 4; d++)
#pragma unroll
    for (int r = 0; r < 4; r++) {
      int t = t0 + w * 16 + lg * 4 + r;
      ow[((size_t)b * 1024 + t) * 512 + h * 64 + d * 16 + lr] = cvt1(oacc[d][r] * inv[r]);
    }
}

extern "C" void kernel_launch(void* const* d_in, const int* in_sizes, int n_in,
                              void* d_out, int out_size, void* d_ws, size_t ws_size,
                              hipStream_t stream) {
  const float* query = (const float*)d_in[0];
  const float* key = (const float*)d_in[1];
  const float* value = (const float*)d_in[2];
  const int* amask = (const int*)d_in[3];
  const float* pos = (const float*)d_in[4];
  const float* Wq = (const float*)d_in[5];
  const float* bq = (const float*)d_in[6];
  const float* Wk = (const float*)d_in[7];
  const float* bk = (const float*)d_in[8];
  const float* Wv = (const float*)d_in[9];
  const float* bv = (const float*)d_in[10];
  const float* Wpos = (const float*)d_in[11];
  const float* Wout = (const float*)d_in[12];
  const float* bout = (const float*)d_in[13];
  const float* pbu = (const float*)d_in[14];
  const float* pbv = (const float*)d_in[15];

  float* out = (float*)d_out;               // [8192,512] f32
  float* cache = out + (size_t)8192 * 512;  // [64,1024,128] f32

  char* ws = (char*)d_ws;
  unsigned short* ws_q = (unsigned short*)(ws);                     // 8.39 MB
  unsigned short* ws_kp = (unsigned short*)(ws + 8388608);          // 8.39 MB (p, then kp in-place)
  unsigned short* ws_vt = (unsigned short*)(ws + 16777216);         // 8.39 MB (V^T bf16)
  unsigned short* ws_o = (unsigned short*)(ws + 25165824);          // 8.39 MB (attn out)
  unsigned short* W4 = ws_o;                                        // 2.10 MB, dead before attn
  float* cbuf = (float*)(ws + 33554432);                            // 0.26 MB
  unsigned long long* mbits = (unsigned long long*)(ws + 33816576); // 1.05 MB
  unsigned short* Woutb = ws_q;                                     // reused after attn

  dim3 blk(256);
  prep_w<<<dim3(128, 4), blk, 0, stream>>>(Wq, Wk, Wv, Wpos, W4);
  gemm_bt<true><<<dim3(64, 8, 4), blk, 0, stream>>>(
      query, key, value, pos, W4, bq, bk, bv, 0, ws_q, cache, ws_vt, ws_kp, nullptr);
  fuse_kp<<<dim3(4096), blk, 0, stream>>>(cache, ws_kp, pbu, pbv, cbuf);
  pack_mask<<<dim3(32768), blk, 0, stream>>>(amask, mbits);
  attn_kernel<<<dim3(512), dim3(512), 0, stream>>>(ws_q, ws_kp, ws_vt, cbuf, mbits, ws_o);
  prep_w<<<dim3(128, 1), blk, 0, stream>>>(Wout, Wout, Wout, Wout, Woutb);
  gemm_bt<false><<<dim3(64, 8, 1), blk, 0, stream>>>(
      ws_o, nullptr, nullptr, nullptr, Woutb, bout, nullptr, nullptr, 4,
      nullptr, nullptr, nullptr, nullptr, out);
}